// Round 7
// baseline (22151.357 us; speedup 1.0000x reference)
//
#include <hip/hip_runtime.h>
#include <cstdint>

__device__ __forceinline__ float b2f(unsigned short u) {
    union { uint32_t i; float f; } w; w.i = ((uint32_t)u) << 16; return w.f;
}
__device__ __forceinline__ unsigned short f2b(float f) {
    union { uint32_t i; float f; } w; w.f = f;
    uint32_t r = (w.i + 0x7FFFu + ((w.i >> 16) & 1u)) >> 16;
    return (unsigned short)r;
}

// ---------------------------------------------------------------------------
// LayerNorm: one wave per row. in f32, out bf16.
// ---------------------------------------------------------------------------
template <int DIM>
__global__ __launch_bounds__(256) void k_ln(const float* __restrict__ in,
                                            const float* __restrict__ g,
                                            const float* __restrict__ b,
                                            unsigned short* __restrict__ out) {
    const int row = blockIdx.x * 4 + (threadIdx.x >> 6);
    const int ln = threadIdx.x & 63;
    constexpr int PL = DIM / 64;
    float v[PL];
    const size_t base = (size_t)row * DIM + (size_t)ln * PL;
#pragma unroll
    for (int c = 0; c < PL; ++c) v[c] = in[base + c];
    float s = 0.f, s2 = 0.f;
#pragma unroll
    for (int c = 0; c < PL; ++c) { s += v[c]; s2 += v[c] * v[c]; }
    for (int o = 1; o < 64; o <<= 1) { s += __shfl_xor(s, o); s2 += __shfl_xor(s2, o); }
    const float mean = s / DIM;
    const float rstd = rsqrtf(s2 / DIM - mean * mean + 1e-5f);
#pragma unroll
    for (int c = 0; c < PL; ++c) {
        const int kk = ln * PL + c;
        out[(size_t)row * DIM + kk] = f2b((v[c] - mean) * rstd * g[kk] + b[kk]);
    }
}

// ---------------------------------------------------------------------------
// silu(emb[:,0,:]) -> se (128x1024 bf16). emb f32.
// ---------------------------------------------------------------------------
__global__ __launch_bounds__(256) void k_silu(const float* __restrict__ emb,
                                              unsigned short* __restrict__ se) {
    const int i = blockIdx.x * 256 + threadIdx.x;   // 131072 threads
    const int b = i >> 10, k = i & 1023;
    const float f = emb[(size_t)b * (243 * 1024) + k];
    se[i] = f2b(f / (1.f + __expf(-f)));
}

// ---------------------------------------------------------------------------
// Naive GEMM, bf16 out: C[t,d] = bias[d] + sum_k A[t,k]*W[k,d]
// A bf16 (ws), W/bias f32 (inputs)
// ---------------------------------------------------------------------------
__global__ __launch_bounds__(256) void k_gn(const unsigned short* __restrict__ A,
                                            const float* __restrict__ W,
                                            const float* __restrict__ bias,
                                            unsigned short* __restrict__ C,
                                            long MN, int N, int K) {
    const long idx = (long)blockIdx.x * 256 + threadIdx.x;
    if (idx >= MN) return;
    const long t = idx / N;
    const int d = (int)(idx - t * N);
    float acc = bias[d];
    for (int k = 0; k < K; ++k)
        acc += b2f(A[(size_t)t * K + k]) * W[(size_t)k * N + d];
    C[idx] = f2b(acc);
}

// f32-out variant (eo)
__global__ __launch_bounds__(256) void k_gnf(const unsigned short* __restrict__ A,
                                             const float* __restrict__ W,
                                             const float* __restrict__ bias,
                                             float* __restrict__ C,
                                             long MN, int N, int K) {
    const long idx = (long)blockIdx.x * 256 + threadIdx.x;
    if (idx >= MN) return;
    const long t = idx / N;
    const int d = (int)(idx - t * N);
    float acc = bias[d];
    for (int k = 0; k < K; ++k)
        acc += b2f(A[(size_t)t * K + k]) * W[(size_t)k * N + d];
    C[idx] = acc;
}

// final GEMM: out f32 = bias + A@Wo + x (residual, f32)
__global__ __launch_bounds__(256) void k_gno(const unsigned short* __restrict__ A,
                                             const float* __restrict__ W,
                                             const float* __restrict__ bias,
                                             const float* __restrict__ X,
                                             float* __restrict__ C,
                                             long MN, int N, int K) {
    const long idx = (long)blockIdx.x * 256 + threadIdx.x;
    if (idx >= MN) return;
    const long t = idx / N;
    const int d = (int)(idx - t * N);
    float acc = bias[d];
    for (int k = 0; k < K; ++k)
        acc += b2f(A[(size_t)t * K + k]) * W[(size_t)k * N + d];
    C[idx] = acc + X[idx];
}

// ---------------------------------------------------------------------------
// Scalar attention: one thread per (b,t,h). All bf16 ws buffers.
// ---------------------------------------------------------------------------
__global__ __launch_bounds__(256) void k_attn(const unsigned short* __restrict__ Q,
                                              const unsigned short* __restrict__ K_,
                                              const unsigned short* __restrict__ V,
                                              unsigned short* __restrict__ Y) {
    const int idx = blockIdx.x * 256 + threadIdx.x;
    if (idx >= 128 * 243 * 16) return;
    const int b = idx / (243 * 16);
    const int r = idx - b * (243 * 16);
    const int t = r >> 4, h = r & 15;
    const size_t qo = ((size_t)b * 243 + t) * 1024 + h * 64;
    const size_t kvb = (size_t)b * 77 * 1024 + h * 64;
    float p[77];
    float mx = -1e30f;
    for (int n = 0; n < 77; ++n) {
        const size_t ko = kvb + (size_t)n * 1024;
        float acc = 0.f;
        for (int d = 0; d < 64; ++d) acc += b2f(Q[qo + d]) * b2f(K_[ko + d]);
        p[n] = acc * 0.125f;
        mx = fmaxf(mx, p[n]);
    }
    float ss = 0.f;
    for (int n = 0; n < 77; ++n) { p[n] = __expf(p[n] - mx); ss += p[n]; }
    const float inv = 1.f / ss;
    for (int dc = 0; dc < 8; ++dc) {
        float ya[8] = {0.f, 0.f, 0.f, 0.f, 0.f, 0.f, 0.f, 0.f};
        for (int n = 0; n < 77; ++n) {
            const float pv = p[n];
            const size_t vo = kvb + (size_t)n * 1024 + dc * 8;
#pragma unroll
            for (int j = 0; j < 8; ++j) ya[j] += pv * b2f(V[vo + j]);
        }
#pragma unroll
        for (int j = 0; j < 8; ++j) Y[qo + dc * 8 + j] = f2b(ya[j] * inv);
    }
}

// ---------------------------------------------------------------------------
// Stylization: act = silu( LN2(y)*(1+scale) + shift ). y bf16, eo f32, g/b f32.
// ---------------------------------------------------------------------------
__global__ __launch_bounds__(256) void k_act(const unsigned short* __restrict__ y,
                                             const float* __restrict__ eo,
                                             const float* __restrict__ g,
                                             const float* __restrict__ b,
                                             unsigned short* __restrict__ out) {
    const int row = blockIdx.x * 4 + (threadIdx.x >> 6);
    const int ln = threadIdx.x & 63;
    const int bb = row / 243;
    float v[16];
    const size_t base = (size_t)row * 1024 + ln * 16;
#pragma unroll
    for (int c = 0; c < 16; ++c) v[c] = b2f(y[base + c]);
    float s = 0.f, s2 = 0.f;
#pragma unroll
    for (int c = 0; c < 16; ++c) { s += v[c]; s2 += v[c] * v[c]; }
    for (int o = 1; o < 64; o <<= 1) { s += __shfl_xor(s, o); s2 += __shfl_xor(s2, o); }
    const float mean = s / 1024.f;
    const float rstd = rsqrtf(s2 / 1024.f - mean * mean + 1e-5f);
#pragma unroll
    for (int c = 0; c < 16; ++c) {
        const int kk = ln * 16 + c;
        const float nl = (v[c] - mean) * rstd * g[kk] + b[kk];
        const float hh = nl * (1.f + eo[(size_t)bb * 2048 + kk]) + eo[(size_t)bb * 2048 + 1024 + kk];
        out[base + c] = f2b(hh / (1.f + __expf(-hh)));
    }
}

// ---------------------------------------------------------------------------
extern "C" void kernel_launch(void* const* d_in, const int* in_sizes, int n_in,
                              void* d_out, int out_size, void* d_ws, size_t ws_size,
                              hipStream_t stream) {
    (void)in_sizes; (void)n_in; (void)out_size; (void)ws_size;

    const float* x     = (const float*)d_in[0];
    const float* xf    = (const float*)d_in[1];
    const float* emb   = (const float*)d_in[2];
    const float* ln_g  = (const float*)d_in[3];
    const float* ln_b  = (const float*)d_in[4];
    const float* tln_g = (const float*)d_in[5];
    const float* tln_b = (const float*)d_in[6];
    const float* Wq    = (const float*)d_in[7];
    const float* bq    = (const float*)d_in[8];
    const float* Wk    = (const float*)d_in[9];
    const float* bk    = (const float*)d_in[10];
    const float* Wv    = (const float*)d_in[11];
    const float* bv    = (const float*)d_in[12];
    const float* We    = (const float*)d_in[13];
    const float* be    = (const float*)d_in[14];
    const float* ln2_g = (const float*)d_in[15];
    const float* ln2_b = (const float*)d_in[16];
    const float* Wo    = (const float*)d_in[17];
    const float* bo    = (const float*)d_in[18];

    float* outp = (float*)d_out;

    // ws layout: bf16 intermediates (total 179.2 MB, within proven bound)
    char* ws = (char*)d_ws;
    constexpr size_t o_xn  = 0;                    // 31104x1024 bf16 (later y via alias)
    constexpr size_t o_xfn = o_xn + 63700992;      // 9856x512 bf16
    constexpr size_t o_qb  = o_xfn + 10092544;     // 31104x1024 bf16 (later act)
    constexpr size_t o_kb  = o_qb + 63700992;      // 9856x1024 bf16
    constexpr size_t o_vb  = o_kb + 20185088;      // 9856x1024 bf16
    constexpr size_t o_se  = o_vb + 20185088;      // 128x1024 bf16
    constexpr size_t o_eo  = o_se + 262144;        // 128x2048 f32

    unsigned short* xn   = (unsigned short*)(ws + o_xn);
    unsigned short* yb   = xn;                     // alias: xn dead after Q-proj
    unsigned short* xfn  = (unsigned short*)(ws + o_xfn);
    unsigned short* qb   = (unsigned short*)(ws + o_qb);
    unsigned short* actb = qb;                     // alias: q dead after attention
    unsigned short* kb   = (unsigned short*)(ws + o_kb);
    unsigned short* vb   = (unsigned short*)(ws + o_vb);
    unsigned short* se   = (unsigned short*)(ws + o_se);
    float*          eo   = (float*)(ws + o_eo);

    // LayerNorms (f32 in -> bf16 ws)
    k_ln<1024><<<7776, 256, 0, stream>>>(x, ln_g, ln_b, xn);
    k_ln<512><<<2464, 256, 0, stream>>>(xf, tln_g, tln_b, xfn);

    // emb path
    k_silu<<<512, 256, 0, stream>>>(emb, se);
    k_gnf<<<1024, 256, 0, stream>>>(se, We, be, eo, 262144L, 2048, 1024);

    // projections
    k_gn<<<124416, 256, 0, stream>>>(xn, Wq, bq, qb, 31850496L, 1024, 1024);
    k_gn<<<39424, 256, 0, stream>>>(xfn, Wk, bk, kb, 10092544L, 1024, 512);
    k_gn<<<39424, 256, 0, stream>>>(xfn, Wv, bv, vb, 10092544L, 1024, 512);

    // attention (writes yb = xn alias)
    k_attn<<<1944, 256, 0, stream>>>(qb, kb, vb, yb);

    // stylization (writes actb = qb alias)
    k_act<<<7776, 256, 0, stream>>>(yb, eo, ln2_g, ln2_b, actb);

    // output projection + residual -> d_out (f32)
    k_gno<<<124416, 256, 0, stream>>>(actb, Wo, bo, x, outp, 31850496L, 1024, 1024);
}

// Round 8
// 4911.864 us; speedup vs baseline: 4.5098x; 4.5098x over previous
//
#include <hip/hip_runtime.h>
#include <cstdint>

typedef __attribute__((ext_vector_type(8))) __bf16 bf16x8;
typedef __attribute__((ext_vector_type(4))) float f32x4;

__device__ __forceinline__ float b2f(unsigned short u) {
    union { uint32_t i; float f; } w; w.i = ((uint32_t)u) << 16; return w.f;
}
__device__ __forceinline__ unsigned short f2b(float f) {
    union { uint32_t i; float f; } w; w.f = f;
    uint32_t r = (w.i + 0x7FFFu + ((w.i >> 16) & 1u)) >> 16;
    return (unsigned short)r;
}

__global__ void k_zero(int* f) { if (threadIdx.x < 8) f[threadIdx.x] = 0; }

// ---------------------------------------------------------------------------
// Weight convert+transpose: W f32 (R x C) -> Wt bf16 (C x R)
// ---------------------------------------------------------------------------
__global__ __launch_bounds__(256) void k_cvt(const float* __restrict__ in,
                                             unsigned short* __restrict__ out,
                                             int R, int C) {
    __shared__ float s[32][33];
    const int c0 = blockIdx.x * 32, r0 = blockIdx.y * 32;
    const int tx = threadIdx.x & 31, ty = threadIdx.x >> 5;
#pragma unroll
    for (int i = 0; i < 4; ++i)
        s[ty + i * 8][tx] = in[(size_t)(r0 + ty + i * 8) * C + c0 + tx];
    __syncthreads();
#pragma unroll
    for (int i = 0; i < 4; ++i)
        out[(size_t)(c0 + ty + i * 8) * R + r0 + tx] = f2b(s[tx][ty + i * 8]);
}

// ---------------------------------------------------------------------------
// LayerNorm f32 -> bf16, one wave per row
// ---------------------------------------------------------------------------
template <int DIM>
__global__ __launch_bounds__(256) void k_ln(const float* __restrict__ in,
                                            const float* __restrict__ g,
                                            const float* __restrict__ b,
                                            unsigned short* __restrict__ out) {
    const int row = blockIdx.x * 4 + (threadIdx.x >> 6);
    const int ln = threadIdx.x & 63;
    constexpr int PL = DIM / 64;
    float v[PL];
    const size_t base = (size_t)row * DIM + (size_t)ln * PL;
#pragma unroll
    for (int c = 0; c < PL; ++c) v[c] = in[base + c];
    float s = 0.f, s2 = 0.f;
#pragma unroll
    for (int c = 0; c < PL; ++c) { s += v[c]; s2 += v[c] * v[c]; }
    for (int o = 1; o < 64; o <<= 1) { s += __shfl_xor(s, o); s2 += __shfl_xor(s2, o); }
    const float mean = s / DIM;
    const float rstd = rsqrtf(s2 / DIM - mean * mean + 1e-5f);
#pragma unroll
    for (int c = 0; c < PL; ++c) {
        const int kk = ln * PL + c;
        out[(size_t)row * DIM + kk] = f2b((v[c] - mean) * rstd * g[kk] + b[kk]);
    }
}

__global__ __launch_bounds__(256) void k_silu(const float* __restrict__ emb,
                                              unsigned short* __restrict__ se) {
    const int i = blockIdx.x * 256 + threadIdx.x;
    const int b = i >> 10, k = i & 1023;
    const float f = emb[(size_t)b * (243 * 1024) + k];
    se[i] = f2b(f / (1.f + __expf(-f)));
}

// ---------------------------------------------------------------------------
// MFMA GEMM: C = A[M,K](bf16) @ Bt[N,K]^T(bf16); bias f32.
// EPI 0: C0 bf16 = acc+bias0 | EPI 1: Cf f32 = acc+bias0+X | EPI 2: KV split
// EPI 3: Cf f32 = acc+bias0
// 128x128 tile, BK=64, 4 waves, reg-staged LDS with write-side XOR swizzle.
// ---------------------------------------------------------------------------
template <int EPI>
__global__ __launch_bounds__(256, 2) void k_mm(
    const unsigned short* __restrict__ A, const unsigned short* __restrict__ Bt,
    const float* __restrict__ bias0, const float* __restrict__ bias1,
    unsigned short* __restrict__ C0, unsigned short* __restrict__ C1,
    float* __restrict__ Cf, const float* __restrict__ X,
    int N, int K) {
    __shared__ __align__(16) unsigned short sA[128 * 64];
    __shared__ __align__(16) unsigned short sB[128 * 64];
    const int tid = threadIdx.x, wv = tid >> 6, ln = tid & 63;
    const int wm = wv >> 1, wn = wv & 1;
    const int ln15 = ln & 15, lg = ln >> 4;
    const int m0 = blockIdx.x * 128, n0 = blockIdx.y * 128;

    const f32x4 fz = {0.f, 0.f, 0.f, 0.f};
    f32x4 acc[4][4];
#pragma unroll
    for (int i = 0; i < 4; ++i)
#pragma unroll
        for (int j = 0; j < 4; ++j) acc[i][j] = fz;

    const int lrow = ln >> 3;
    const int lslot = ln & 7;
    const unsigned short* ga = A + (size_t)(m0 + wv * 32 + lrow) * K + lslot * 8;
    const unsigned short* gb = Bt + (size_t)(n0 + wv * 32 + lrow) * K + lslot * 8;
    char* const wA = (char*)sA + (wv * 32 + lrow) * 128 + ((lslot ^ lrow) * 16);
    char* const wB = (char*)sB + (wv * 32 + lrow) * 128 + ((lslot ^ lrow) * 16);

    for (int k0 = 0; k0 < K; k0 += 64) {
        uint4 ra[4], rb[4];
#pragma unroll
        for (int i = 0; i < 4; ++i) {
            ra[i] = *(const uint4*)(ga + k0 + (size_t)i * 8 * K);
            rb[i] = *(const uint4*)(gb + k0 + (size_t)i * 8 * K);
        }
        __syncthreads();
#pragma unroll
        for (int i = 0; i < 4; ++i) {
            *(uint4*)(wA + i * 8 * 128) = ra[i];
            *(uint4*)(wB + i * 8 * 128) = rb[i];
        }
        __syncthreads();
        bf16x8 af[4][2], bf[4][2];
#pragma unroll
        for (int i = 0; i < 4; ++i) {
            const int ra2 = wm * 64 + i * 16 + ln15;
            const int rb2 = wn * 64 + i * 16 + ln15;
#pragma unroll
            for (int ks = 0; ks < 2; ++ks) {
                const int slot = ks * 4 + lg;
                af[i][ks] = *(const bf16x8*)(sA + ra2 * 64 + ((slot ^ (ra2 & 7)) * 8));
                bf[i][ks] = *(const bf16x8*)(sB + rb2 * 64 + ((slot ^ (rb2 & 7)) * 8));
            }
        }
#pragma unroll
        for (int mi = 0; mi < 4; ++mi)
#pragma unroll
            for (int ni = 0; ni < 4; ++ni) {
                acc[mi][ni] = __builtin_amdgcn_mfma_f32_16x16x32_bf16(af[mi][0], bf[ni][0], acc[mi][ni], 0, 0, 0);
                acc[mi][ni] = __builtin_amdgcn_mfma_f32_16x16x32_bf16(af[mi][1], bf[ni][1], acc[mi][ni], 0, 0, 0);
            }
    }

    const int colB = n0 + wn * 64;
    const int rowB = m0 + wm * 64;
#pragma unroll
    for (int mi = 0; mi < 4; ++mi) {
#pragma unroll
        for (int ni = 0; ni < 4; ++ni) {
            const int col = colB + ni * 16 + ln15;
            const int row = rowB + mi * 16 + lg * 4;
            float bvv;
            if (EPI == 2) bvv = (col < 1024) ? bias0[col] : bias1[col - 1024];
            else bvv = bias0[col];
#pragma unroll
            for (int r = 0; r < 4; ++r) {
                const float v = acc[mi][ni][r] + bvv;
                if (EPI == 0) {
                    C0[(size_t)(row + r) * N + col] = f2b(v);
                } else if (EPI == 1) {
                    Cf[(size_t)(row + r) * N + col] = v + X[(size_t)(row + r) * N + col];
                } else if (EPI == 2) {
                    if (col < 1024) C0[(size_t)(row + r) * 1024 + col] = f2b(v);
                    else C1[(size_t)(row + r) * 1024 + (col - 1024)] = f2b(v);
                } else {
                    Cf[(size_t)(row + r) * N + col] = v;
                }
            }
        }
    }
}

// ---------------------------------------------------------------------------
// Sampled scalar verifier vs bf16 operands. MODE 0: C bf16; 1: Cf f32; 2: Cf+X
// NaN-safe: flags unless |diff| <= thr.
// ---------------------------------------------------------------------------
template <int MODE>
__global__ __launch_bounds__(256) void k_vmm(const unsigned short* __restrict__ A,
                                             const unsigned short* __restrict__ Wt,
                                             const float* __restrict__ bias,
                                             const unsigned short* __restrict__ C,
                                             const float* __restrict__ Cf,
                                             const float* __restrict__ X,
                                             int M, int N, int K, float thr, int* flag) {
    const unsigned s = threadIdx.x;
    int bad = 0;
    for (unsigned j = 0; j < 2; ++j) {
        const int t = (int)((s * 7919u + j * 104729u + 5u) % (unsigned)M);
        const int d = (int)((s * 613u + j * 1013904223u) % (unsigned)N);
        float acc = bias[d];
        for (int k = 0; k < K; ++k)
            acc += b2f(A[(size_t)t * K + k]) * b2f(Wt[(size_t)d * K + k]);
        float actv;
        if (MODE == 0) actv = b2f(C[(size_t)t * N + d]);
        else if (MODE == 1) actv = Cf[(size_t)t * N + d];
        else { acc += X[(size_t)t * N + d]; actv = Cf[(size_t)t * N + d]; }
        if (!(fabsf(actv - acc) <= thr)) bad = 1;
    }
    if (bad) atomicOr(flag, 1);
}

// ---------------------------------------------------------------------------
// Flag-gated scalar fallbacks (round-7 semantics; no-op when flag==0)
// ---------------------------------------------------------------------------
__global__ __launch_bounds__(256) void k_gn_fb(const unsigned short* __restrict__ A,
                                               const float* __restrict__ W,
                                               const float* __restrict__ bias,
                                               unsigned short* __restrict__ C,
                                               long MN, int N, int K,
                                               const int* __restrict__ flag) {
    if (*flag == 0) return;
    const long idx = (long)blockIdx.x * 256 + threadIdx.x;
    if (idx >= MN) return;
    const long t = idx / N;
    const int d = (int)(idx - t * N);
    float acc = bias[d];
    for (int k = 0; k < K; ++k)
        acc += b2f(A[(size_t)t * K + k]) * W[(size_t)k * N + d];
    C[idx] = f2b(acc);
}

__global__ __launch_bounds__(256) void k_gnf_fb(const unsigned short* __restrict__ A,
                                                const float* __restrict__ W,
                                                const float* __restrict__ bias,
                                                float* __restrict__ C,
                                                long MN, int N, int K,
                                                const int* __restrict__ flag) {
    if (*flag == 0) return;
    const long idx = (long)blockIdx.x * 256 + threadIdx.x;
    if (idx >= MN) return;
    const long t = idx / N;
    const int d = (int)(idx - t * N);
    float acc = bias[d];
    for (int k = 0; k < K; ++k)
        acc += b2f(A[(size_t)t * K + k]) * W[(size_t)k * N + d];
    C[idx] = acc;
}

__global__ __launch_bounds__(256) void k_gno_fb(const unsigned short* __restrict__ A,
                                                const float* __restrict__ W,
                                                const float* __restrict__ bias,
                                                const float* __restrict__ X,
                                                float* __restrict__ C,
                                                long MN, int N, int K,
                                                const int* __restrict__ flag) {
    if (*flag == 0) return;
    const long idx = (long)blockIdx.x * 256 + threadIdx.x;
    if (idx >= MN) return;
    const long t = idx / N;
    const int d = (int)(idx - t * N);
    float acc = bias[d];
    for (int k = 0; k < K; ++k)
        acc += b2f(A[(size_t)t * K + k]) * W[(size_t)k * N + d];
    C[idx] = acc + X[idx];
}

// ---------------------------------------------------------------------------
// Scalar attention: one thread per (b,t,h) [round-7 proven]
// ---------------------------------------------------------------------------
__global__ __launch_bounds__(256) void k_attn(const unsigned short* __restrict__ Q,
                                              const unsigned short* __restrict__ K_,
                                              const unsigned short* __restrict__ V,
                                              unsigned short* __restrict__ Y) {
    const int idx = blockIdx.x * 256 + threadIdx.x;
    if (idx >= 128 * 243 * 16) return;
    const int b = idx / (243 * 16);
    const int r = idx - b * (243 * 16);
    const int t = r >> 4, h = r & 15;
    const size_t qo = ((size_t)b * 243 + t) * 1024 + h * 64;
    const size_t kvb = (size_t)b * 77 * 1024 + h * 64;
    float p[77];
    float mx = -1e30f;
    for (int n = 0; n < 77; ++n) {
        const size_t ko = kvb + (size_t)n * 1024;
        float acc = 0.f;
        for (int d = 0; d < 64; ++d) acc += b2f(Q[qo + d]) * b2f(K_[ko + d]);
        p[n] = acc * 0.125f;
        mx = fmaxf(mx, p[n]);
    }
    float ss = 0.f;
    for (int n = 0; n < 77; ++n) { p[n] = __expf(p[n] - mx); ss += p[n]; }
    const float inv = 1.f / ss;
    for (int dc = 0; dc < 8; ++dc) {
        float ya[8] = {0.f, 0.f, 0.f, 0.f, 0.f, 0.f, 0.f, 0.f};
        for (int n = 0; n < 77; ++n) {
            const float pv = p[n];
            const size_t vo = kvb + (size_t)n * 1024 + dc * 8;
#pragma unroll
            for (int j = 0; j < 8; ++j) ya[j] += pv * b2f(V[vo + j]);
        }
#pragma unroll
        for (int j = 0; j < 8; ++j) Y[qo + dc * 8 + j] = f2b(ya[j] * inv);
    }
}

// ---------------------------------------------------------------------------
// Stylization [round-7 proven]
// ---------------------------------------------------------------------------
__global__ __launch_bounds__(256) void k_act(const unsigned short* __restrict__ y,
                                             const float* __restrict__ eo,
                                             const float* __restrict__ g,
                                             const float* __restrict__ b,
                                             unsigned short* __restrict__ out) {
    const int row = blockIdx.x * 4 + (threadIdx.x >> 6);
    const int ln = threadIdx.x & 63;
    const int bb = row / 243;
    float v[16];
    const size_t base = (size_t)row * 1024 + ln * 16;
#pragma unroll
    for (int c = 0; c < 16; ++c) v[c] = b2f(y[base + c]);
    float s = 0.f, s2 = 0.f;
#pragma unroll
    for (int c = 0; c < 16; ++c) { s += v[c]; s2 += v[c] * v[c]; }
    for (int o = 1; o < 64; o <<= 1) { s += __shfl_xor(s, o); s2 += __shfl_xor(s2, o); }
    const float mean = s / 1024.f;
    const float rstd = rsqrtf(s2 / 1024.f - mean * mean + 1e-5f);
#pragma unroll
    for (int c = 0; c < 16; ++c) {
        const int kk = ln * 16 + c;
        const float nl = (v[c] - mean) * rstd * g[kk] + b[kk];
        const float hh = nl * (1.f + eo[(size_t)bb * 2048 + kk]) + eo[(size_t)bb * 2048 + 1024 + kk];
        out[base + c] = f2b(hh / (1.f + __expf(-hh)));
    }
}

// ---------------------------------------------------------------------------
extern "C" void kernel_launch(void* const* d_in, const int* in_sizes, int n_in,
                              void* d_out, int out_size, void* d_ws, size_t ws_size,
                              hipStream_t stream) {
    (void)in_sizes; (void)n_in; (void)out_size; (void)ws_size;

    const float* x     = (const float*)d_in[0];
    const float* xf    = (const float*)d_in[1];
    const float* emb   = (const float*)d_in[2];
    const float* ln_g  = (const float*)d_in[3];
    const float* ln_b  = (const float*)d_in[4];
    const float* tln_g = (const float*)d_in[5];
    const float* tln_b = (const float*)d_in[6];
    const float* Wq    = (const float*)d_in[7];
    const float* bq    = (const float*)d_in[8];
    const float* Wk    = (const float*)d_in[9];
    const float* bk    = (const float*)d_in[10];
    const float* Wv    = (const float*)d_in[11];
    const float* bv    = (const float*)d_in[12];
    const float* We    = (const float*)d_in[13];
    const float* be    = (const float*)d_in[14];
    const float* ln2_g = (const float*)d_in[15];
    const float* ln2_b = (const float*)d_in[16];
    const float* Wo    = (const float*)d_in[17];
    const float* bo    = (const float*)d_in[18];
    float* outp = (float*)d_out;

    char* ws = (char*)d_ws;
    constexpr size_t o_wq   = 0;                    // 1024x1024 bf16
    constexpr size_t o_wkv  = o_wq + 2097152;       // 2048x512 bf16
    constexpr size_t o_we   = o_wkv + 2097152;      // 2048x1024 bf16
    constexpr size_t o_wo   = o_we + 4194304;       // 1024x1024 bf16
    constexpr size_t o_se   = o_wo + 2097152;       // 128x1024 bf16
    constexpr size_t o_eo   = o_se + 262144;        // 128x2048 f32
    constexpr size_t o_flag = o_eo + 1048576;       // 8 ints
    constexpr size_t o_xn   = o_flag + 256;         // 31104x1024 bf16 (later y)
    constexpr size_t o_qb   = o_xn + 63700992;      // 31104x1024 bf16 (later act)
    constexpr size_t o_xfn  = o_qb + 63700992;      // 9856x512 bf16
    constexpr size_t o_kb   = o_xfn + 10092544;     // 9856x1024 bf16
    constexpr size_t o_vb   = o_kb + 20185088;      // 9856x1024 bf16

    unsigned short* wqt  = (unsigned short*)(ws + o_wq);
    unsigned short* wkvt = (unsigned short*)(ws + o_wkv);
    unsigned short* wet  = (unsigned short*)(ws + o_we);
    unsigned short* wot  = (unsigned short*)(ws + o_wo);
    unsigned short* se   = (unsigned short*)(ws + o_se);
    float*          eo   = (float*)(ws + o_eo);
    int*            flg  = (int*)(ws + o_flag);
    unsigned short* xn   = (unsigned short*)(ws + o_xn);
    unsigned short* yb   = xn;                      // alias: xn dead after Q-GEMM
    unsigned short* qb   = (unsigned short*)(ws + o_qb);
    unsigned short* actb = qb;                      // alias: q dead after attention
    unsigned short* xfn  = (unsigned short*)(ws + o_xfn);
    unsigned short* kb   = (unsigned short*)(ws + o_kb);
    unsigned short* vb   = (unsigned short*)(ws + o_vb);

    k_zero<<<1, 64, 0, stream>>>(flg);

    // pre-passes
    k_ln<1024><<<7776, 256, 0, stream>>>(x, ln_g, ln_b, xn);
    k_ln<512><<<2464, 256, 0, stream>>>(xf, tln_g, tln_b, xfn);
    k_silu<<<512, 256, 0, stream>>>(emb, se);
    k_cvt<<<dim3(32, 32), 256, 0, stream>>>(Wq, wqt, 1024, 1024);
    k_cvt<<<dim3(32, 16), 256, 0, stream>>>(Wk, wkvt, 512, 1024);
    k_cvt<<<dim3(32, 16), 256, 0, stream>>>(Wv, wkvt + 1024 * 512, 512, 1024);
    k_cvt<<<dim3(64, 32), 256, 0, stream>>>(We, wet, 1024, 2048);
    k_cvt<<<dim3(32, 32), 256, 0, stream>>>(Wo, wot, 1024, 1024);

    // eo = silu(emb0) @ We + be   (f32 out)
    k_mm<3><<<dim3(1, 16), 256, 0, stream>>>(se, wet, be, nullptr,
                                             nullptr, nullptr, eo, nullptr, 2048, 1024);
    k_vmm<1><<<1, 256, 0, stream>>>(se, wet, be, nullptr, eo, nullptr,
                                    128, 2048, 1024, 0.05f, flg + 3);
    k_gnf_fb<<<1024, 256, 0, stream>>>(se, We, be, eo, 262144L, 2048, 1024, flg + 3);

    // Q projection
    k_mm<0><<<dim3(243, 8), 256, 0, stream>>>(xn, wqt, bq, nullptr,
                                              qb, nullptr, nullptr, nullptr, 1024, 1024);
    k_vmm<0><<<1, 256, 0, stream>>>(xn, wqt, bq, qb, nullptr, nullptr,
                                    31104, 1024, 1024, 0.1f, flg + 0);
    k_gn_fb<<<124416, 256, 0, stream>>>(xn, Wq, bq, qb, 31850496L, 1024, 1024, flg + 0);

    // KV projection (fused, split outputs)
    k_mm<2><<<dim3(77, 16), 256, 0, stream>>>(xfn, wkvt, bk, bv,
                                              kb, vb, nullptr, nullptr, 2048, 512);
    k_vmm<0><<<1, 256, 0, stream>>>(xfn, wkvt, bk, kb, nullptr, nullptr,
                                    9856, 1024, 512, 0.1f, flg + 1);
    k_vmm<0><<<1, 256, 0, stream>>>(xfn, wkvt + 1024 * 512, bv, vb, nullptr, nullptr,
                                    9856, 1024, 512, 0.1f, flg + 2);
    k_gn_fb<<<39424, 256, 0, stream>>>(xfn, Wk, bk, kb, 10092544L, 1024, 512, flg + 1);
    k_gn_fb<<<39424, 256, 0, stream>>>(xfn, Wv, bv, vb, 10092544L, 1024, 512, flg + 2);

    // attention (writes yb = xn alias)
    k_attn<<<1944, 256, 0, stream>>>(qb, kb, vb, yb);

    // stylization (writes actb = qb alias)
    k_act<<<7776, 256, 0, stream>>>(yb, eo, ln2_g, ln2_b, actb);

    // output projection + residual -> d_out (f32)
    k_mm<1><<<dim3(243, 8), 256, 0, stream>>>(actb, wot, bo, nullptr,
                                              nullptr, nullptr, outp, x, 1024, 1024);
    k_vmm<2><<<1, 256, 0, stream>>>(actb, wot, bo, nullptr, outp, x,
                                    31104, 1024, 1024, 0.05f, flg + 4);
    k_gno_fb<<<124416, 256, 0, stream>>>(actb, Wo, bo, x, outp, 31850496L, 1024, 1024, flg + 4);
}

// Round 9
// 3128.504 us; speedup vs baseline: 7.0805x; 1.5700x over previous
//
#include <hip/hip_runtime.h>
#include <cstdint>

typedef __attribute__((ext_vector_type(8))) __bf16 bf16x8;
typedef __attribute__((ext_vector_type(4))) float f32x4;

__device__ __forceinline__ float b2f(unsigned short u) {
    union { uint32_t i; float f; } w; w.i = ((uint32_t)u) << 16; return w.f;
}
__device__ __forceinline__ unsigned short f2b(float f) {
    union { uint32_t i; float f; } w; w.f = f;
    uint32_t r = (w.i + 0x7FFFu + ((w.i >> 16) & 1u)) >> 16;
    return (unsigned short)r;
}

__global__ void k_zero(int* f) { if (threadIdx.x < 8) f[threadIdx.x] = 0; }

// ---------------------------------------------------------------------------
// Weight convert+transpose: W f32 (R x C) -> Wt bf16 (C x R)
// ---------------------------------------------------------------------------
__global__ __launch_bounds__(256) void k_cvt(const float* __restrict__ in,
                                             unsigned short* __restrict__ out,
                                             int R, int C) {
    __shared__ float s[32][33];
    const int c0 = blockIdx.x * 32, r0 = blockIdx.y * 32;
    const int tx = threadIdx.x & 31, ty = threadIdx.x >> 5;
#pragma unroll
    for (int i = 0; i < 4; ++i)
        s[ty + i * 8][tx] = in[(size_t)(r0 + ty + i * 8) * C + c0 + tx];
    __syncthreads();
#pragma unroll
    for (int i = 0; i < 4; ++i)
        out[(size_t)(c0 + ty + i * 8) * R + r0 + tx] = f2b(s[tx][ty + i * 8]);
}

// ---------------------------------------------------------------------------
// LayerNorm f32 -> bf16, one wave per row
// ---------------------------------------------------------------------------
template <int DIM>
__global__ __launch_bounds__(256) void k_ln(const float* __restrict__ in,
                                            const float* __restrict__ g,
                                            const float* __restrict__ b,
                                            unsigned short* __restrict__ out) {
    const int row = blockIdx.x * 4 + (threadIdx.x >> 6);
    const int ln = threadIdx.x & 63;
    constexpr int PL = DIM / 64;
    float v[PL];
    const size_t base = (size_t)row * DIM + (size_t)ln * PL;
#pragma unroll
    for (int c = 0; c < PL; ++c) v[c] = in[base + c];
    float s = 0.f, s2 = 0.f;
#pragma unroll
    for (int c = 0; c < PL; ++c) { s += v[c]; s2 += v[c] * v[c]; }
    for (int o = 1; o < 64; o <<= 1) { s += __shfl_xor(s, o); s2 += __shfl_xor(s2, o); }
    const float mean = s / DIM;
    const float rstd = rsqrtf(s2 / DIM - mean * mean + 1e-5f);
#pragma unroll
    for (int c = 0; c < PL; ++c) {
        const int kk = ln * PL + c;
        out[(size_t)row * DIM + kk] = f2b((v[c] - mean) * rstd * g[kk] + b[kk]);
    }
}

__global__ __launch_bounds__(256) void k_silu(const float* __restrict__ emb,
                                              unsigned short* __restrict__ se) {
    const int i = blockIdx.x * 256 + threadIdx.x;
    const int b = i >> 10, k = i & 1023;
    const float f = emb[(size_t)b * (243 * 1024) + k];
    se[i] = f2b(f / (1.f + __expf(-f)));
}

// ---------------------------------------------------------------------------
// MFMA GEMM (validated round 8): C = A[M,K](bf16) @ Bt[N,K]^T(bf16); bias f32.
// ---------------------------------------------------------------------------
template <int EPI>
__global__ __launch_bounds__(256, 2) void k_mm(
    const unsigned short* __restrict__ A, const unsigned short* __restrict__ Bt,
    const float* __restrict__ bias0, const float* __restrict__ bias1,
    unsigned short* __restrict__ C0, unsigned short* __restrict__ C1,
    float* __restrict__ Cf, const float* __restrict__ X,
    int N, int K) {
    __shared__ __align__(16) unsigned short sA[128 * 64];
    __shared__ __align__(16) unsigned short sB[128 * 64];
    const int tid = threadIdx.x, wv = tid >> 6, ln = tid & 63;
    const int wm = wv >> 1, wn = wv & 1;
    const int ln15 = ln & 15, lg = ln >> 4;
    const int m0 = blockIdx.x * 128, n0 = blockIdx.y * 128;

    const f32x4 fz = {0.f, 0.f, 0.f, 0.f};
    f32x4 acc[4][4];
#pragma unroll
    for (int i = 0; i < 4; ++i)
#pragma unroll
        for (int j = 0; j < 4; ++j) acc[i][j] = fz;

    const int lrow = ln >> 3;
    const int lslot = ln & 7;
    const unsigned short* ga = A + (size_t)(m0 + wv * 32 + lrow) * K + lslot * 8;
    const unsigned short* gb = Bt + (size_t)(n0 + wv * 32 + lrow) * K + lslot * 8;
    char* const wA = (char*)sA + (wv * 32 + lrow) * 128 + ((lslot ^ lrow) * 16);
    char* const wB = (char*)sB + (wv * 32 + lrow) * 128 + ((lslot ^ lrow) * 16);

    for (int k0 = 0; k0 < K; k0 += 64) {
        uint4 ra[4], rb[4];
#pragma unroll
        for (int i = 0; i < 4; ++i) {
            ra[i] = *(const uint4*)(ga + k0 + (size_t)i * 8 * K);
            rb[i] = *(const uint4*)(gb + k0 + (size_t)i * 8 * K);
        }
        __syncthreads();
#pragma unroll
        for (int i = 0; i < 4; ++i) {
            *(uint4*)(wA + i * 8 * 128) = ra[i];
            *(uint4*)(wB + i * 8 * 128) = rb[i];
        }
        __syncthreads();
        bf16x8 af[4][2], bf[4][2];
#pragma unroll
        for (int i = 0; i < 4; ++i) {
            const int ra2 = wm * 64 + i * 16 + ln15;
            const int rb2 = wn * 64 + i * 16 + ln15;
#pragma unroll
            for (int ks = 0; ks < 2; ++ks) {
                const int slot = ks * 4 + lg;
                af[i][ks] = *(const bf16x8*)(sA + ra2 * 64 + ((slot ^ (ra2 & 7)) * 8));
                bf[i][ks] = *(const bf16x8*)(sB + rb2 * 64 + ((slot ^ (rb2 & 7)) * 8));
            }
        }
#pragma unroll
        for (int mi = 0; mi < 4; ++mi)
#pragma unroll
            for (int ni = 0; ni < 4; ++ni) {
                acc[mi][ni] = __builtin_amdgcn_mfma_f32_16x16x32_bf16(af[mi][0], bf[ni][0], acc[mi][ni], 0, 0, 0);
                acc[mi][ni] = __builtin_amdgcn_mfma_f32_16x16x32_bf16(af[mi][1], bf[ni][1], acc[mi][ni], 0, 0, 0);
            }
    }

    const int colB = n0 + wn * 64;
    const int rowB = m0 + wm * 64;
#pragma unroll
    for (int mi = 0; mi < 4; ++mi) {
#pragma unroll
        for (int ni = 0; ni < 4; ++ni) {
            const int col = colB + ni * 16 + ln15;
            const int row = rowB + mi * 16 + lg * 4;
            float bvv;
            if (EPI == 2) bvv = (col < 1024) ? bias0[col] : bias1[col - 1024];
            else bvv = bias0[col];
#pragma unroll
            for (int r = 0; r < 4; ++r) {
                const float v = acc[mi][ni][r] + bvv;
                if (EPI == 0) {
                    C0[(size_t)(row + r) * N + col] = f2b(v);
                } else if (EPI == 1) {
                    Cf[(size_t)(row + r) * N + col] = v + X[(size_t)(row + r) * N + col];
                } else if (EPI == 2) {
                    if (col < 1024) C0[(size_t)(row + r) * 1024 + col] = f2b(v);
                    else C1[(size_t)(row + r) * 1024 + (col - 1024)] = f2b(v);
                } else {
                    Cf[(size_t)(row + r) * N + col] = v;
                }
            }
        }
    }
}

// ---------------------------------------------------------------------------
// Sampled scalar GEMM verifier (NaN-safe)
// ---------------------------------------------------------------------------
template <int MODE>
__global__ __launch_bounds__(256) void k_vmm(const unsigned short* __restrict__ A,
                                             const unsigned short* __restrict__ Wt,
                                             const float* __restrict__ bias,
                                             const unsigned short* __restrict__ C,
                                             const float* __restrict__ Cf,
                                             const float* __restrict__ X,
                                             int M, int N, int K, float thr, int* flag) {
    const unsigned s = threadIdx.x;
    int bad = 0;
    for (unsigned j = 0; j < 2; ++j) {
        const int t = (int)((s * 7919u + j * 104729u + 5u) % (unsigned)M);
        const int d = (int)((s * 613u + j * 1013904223u) % (unsigned)N);
        float acc = bias[d];
        for (int k = 0; k < K; ++k)
            acc += b2f(A[(size_t)t * K + k]) * b2f(Wt[(size_t)d * K + k]);
        float actv;
        if (MODE == 0) actv = b2f(C[(size_t)t * N + d]);
        else if (MODE == 1) actv = Cf[(size_t)t * N + d];
        else { acc += X[(size_t)t * N + d]; actv = Cf[(size_t)t * N + d]; }
        if (!(fabsf(actv - acc) <= thr)) bad = 1;
    }
    if (bad) atomicOr(flag, 1);
}

// ---------------------------------------------------------------------------
// Flag-gated grid-stride scalar fallbacks (no-op when flag==0)
// ---------------------------------------------------------------------------
__global__ __launch_bounds__(256) void k_gn_fb(const unsigned short* __restrict__ A,
                                               const float* __restrict__ W,
                                               const float* __restrict__ bias,
                                               unsigned short* __restrict__ C,
                                               long MN, int N, int K,
                                               const int* __restrict__ flag) {
    if (*flag == 0) return;
    for (long idx = (long)blockIdx.x * 256 + threadIdx.x; idx < MN; idx += (long)gridDim.x * 256) {
        const long t = idx / N;
        const int d = (int)(idx - t * N);
        float acc = bias[d];
        for (int k = 0; k < K; ++k)
            acc += b2f(A[(size_t)t * K + k]) * W[(size_t)k * N + d];
        C[idx] = f2b(acc);
    }
}

__global__ __launch_bounds__(256) void k_gnf_fb(const unsigned short* __restrict__ A,
                                                const float* __restrict__ W,
                                                const float* __restrict__ bias,
                                                float* __restrict__ C,
                                                long MN, int N, int K,
                                                const int* __restrict__ flag) {
    if (*flag == 0) return;
    for (long idx = (long)blockIdx.x * 256 + threadIdx.x; idx < MN; idx += (long)gridDim.x * 256) {
        const long t = idx / N;
        const int d = (int)(idx - t * N);
        float acc = bias[d];
        for (int k = 0; k < K; ++k)
            acc += b2f(A[(size_t)t * K + k]) * W[(size_t)k * N + d];
        C[idx] = acc;
    }
}

__global__ __launch_bounds__(256) void k_gno_fb(const unsigned short* __restrict__ A,
                                                const float* __restrict__ W,
                                                const float* __restrict__ bias,
                                                const float* __restrict__ X,
                                                float* __restrict__ C,
                                                long MN, int N, int K,
                                                const int* __restrict__ flag) {
    if (*flag == 0) return;
    for (long idx = (long)blockIdx.x * 256 + threadIdx.x; idx < MN; idx += (long)gridDim.x * 256) {
        const long t = idx / N;
        const int d = (int)(idx - t * N);
        float acc = bias[d];
        for (int k = 0; k < K; ++k)
            acc += b2f(A[(size_t)t * K + k]) * W[(size_t)k * N + d];
        C[idx] = acc + X[idx];
    }
}

// ---------------------------------------------------------------------------
// MFMA cross-attention: one block per (b,h). T=243(pad 256), N=77(pad 80/96)
// Fragment conventions identical to k_mm (validated).
// ---------------------------------------------------------------------------
__global__ __launch_bounds__(256, 2) void k_attn_m(const unsigned short* __restrict__ Q,
                                                   const unsigned short* __restrict__ Kb,
                                                   const unsigned short* __restrict__ Vb,
                                                   unsigned short* __restrict__ Y) {
    __shared__ __align__(16) unsigned short sK[80 * 64];       // [n][d], XOR-swizzled 16B slots
    __shared__ __align__(16) unsigned short sV[64 * 96];       // V^T [d][n], fully initialized
    __shared__ __align__(16) unsigned short sP[4][16 * 104];   // per-wave P tile
    const int bh = blockIdx.x;
    const int b = bh >> 4, h = bh & 15;
    const int tid = threadIdx.x, wv = tid >> 6, ln = tid & 63;
    const int ln15 = ln & 15, lg = ln >> 4;

    for (int c = tid; c < 640; c += 256) {
        const int n = c >> 3, ci = c & 7;
        uint4 val = make_uint4(0u, 0u, 0u, 0u);
        if (n < 77) val = *(const uint4*)(Kb + (size_t)(b * 77 + n) * 1024 + h * 64 + ci * 8);
        *(uint4*)((char*)sK + n * 128 + ((ci * 16) ^ ((n & 7) << 4))) = val;
    }
    for (int i = tid; i < 64 * 96; i += 256) {
        const int d = i / 96, n = i - d * 96;
        unsigned short val = 0;
        if (n < 77) val = Vb[(size_t)(b * 77 + n) * 1024 + h * 64 + d];
        sV[i] = val;
    }
    for (int i = ln; i < 16 * 24; i += 64) {
        const int rr = i / 24, cc = i - rr * 24;
        sP[wv][rr * 104 + 80 + cc] = 0;
    }
    bf16x8 qf[4][2];
    const size_t qbase = (size_t)b * (243 * 1024) + h * 64;
#pragma unroll
    for (int mi = 0; mi < 4; ++mi) {
        int t = wv * 64 + mi * 16 + ln15;
        if (t > 242) t = 242;
#pragma unroll
        for (int ks = 0; ks < 2; ++ks)
            qf[mi][ks] = *(const bf16x8*)(Q + qbase + (size_t)t * 1024 + ks * 32 + lg * 8);
    }
    __syncthreads();

    const f32x4 fz = {0.f, 0.f, 0.f, 0.f};
    f32x4 yacc[4][4];
#pragma unroll
    for (int i = 0; i < 4; ++i)
#pragma unroll
        for (int j = 0; j < 4; ++j) yacc[i][j] = fz;

#pragma unroll
    for (int mi = 0; mi < 4; ++mi) {
        f32x4 sc[5];
#pragma unroll
        for (int ci = 0; ci < 5; ++ci) sc[ci] = fz;
#pragma unroll
        for (int ci = 0; ci < 5; ++ci) {
            const int n = ci * 16 + ln15;
#pragma unroll
            for (int ks = 0; ks < 2; ++ks) {
                const int kk = ks * 32 + lg * 8;
                bf16x8 kf = *(const bf16x8*)((const char*)sK + n * 128 + ((kk * 2) ^ ((n & 7) << 4)));
                sc[ci] = __builtin_amdgcn_mfma_f32_16x16x32_bf16(qf[mi][ks], kf, sc[ci], 0, 0, 0);
            }
        }
        // softmax over n; row lg*4+r owned by the 16 lanes sharing lg
#pragma unroll
        for (int r = 0; r < 4; ++r) {
            float e[5];
            float mx = -1e30f;
#pragma unroll
            for (int ci = 0; ci < 5; ++ci) {
                const int n = ci * 16 + ln15;
                const float vv = (n < 77) ? sc[ci][r] * 0.125f : -1e30f;
                e[ci] = vv;
                mx = fmaxf(mx, vv);
            }
            mx = fmaxf(mx, __shfl_xor(mx, 1));
            mx = fmaxf(mx, __shfl_xor(mx, 2));
            mx = fmaxf(mx, __shfl_xor(mx, 4));
            mx = fmaxf(mx, __shfl_xor(mx, 8));
            float ssum = 0.f;
#pragma unroll
            for (int ci = 0; ci < 5; ++ci) {
                const int n = ci * 16 + ln15;
                const float ev = (n < 77) ? __expf(e[ci] - mx) : 0.f;
                e[ci] = ev;
                ssum += ev;
            }
            ssum += __shfl_xor(ssum, 1);
            ssum += __shfl_xor(ssum, 2);
            ssum += __shfl_xor(ssum, 4);
            ssum += __shfl_xor(ssum, 8);
            const float inv = 1.f / ssum;
            const int prow = lg * 4 + r;
#pragma unroll
            for (int ci = 0; ci < 5; ++ci)
                sP[wv][prow * 104 + ci * 16 + ln15] = f2b(e[ci] * inv);
        }
        __syncthreads();
        // PV: A = P (16 x 96 incl zero pad), B = V^T fragments
#pragma unroll
        for (int ks = 0; ks < 3; ++ks) {
            bf16x8 pa = *(const bf16x8*)(sP[wv] + ln15 * 104 + ks * 32 + lg * 8);
#pragma unroll
            for (int di = 0; di < 4; ++di) {
                bf16x8 vf = *(const bf16x8*)(sV + (di * 16 + ln15) * 96 + ks * 32 + lg * 8);
                yacc[mi][di] = __builtin_amdgcn_mfma_f32_16x16x32_bf16(pa, vf, yacc[mi][di], 0, 0, 0);
            }
        }
        __syncthreads();
    }
    const size_t ybase = (size_t)b * (243 * 1024) + h * 64;
#pragma unroll
    for (int mi = 0; mi < 4; ++mi)
#pragma unroll
        for (int di = 0; di < 4; ++di)
#pragma unroll
            for (int r = 0; r < 4; ++r) {
                const int t = wv * 64 + mi * 16 + lg * 4 + r;
                if (t < 243) Y[ybase + (size_t)t * 1024 + di * 16 + ln15] = f2b(yacc[mi][di][r]);
            }
}

// sampled scalar attention verifier (NaN-safe)
__global__ __launch_bounds__(64) void k_vattn(const unsigned short* __restrict__ Q,
                                              const unsigned short* __restrict__ K_,
                                              const unsigned short* __restrict__ V,
                                              const unsigned short* __restrict__ Y,
                                              int* flag) {
    const unsigned s = threadIdx.x;
    const int b = (int)((s * 2654435761u) % 128u);
    const int t = (int)((s * 40503u + 3u) % 243u);
    const int h = (int)((s * 7u + 1u) % 16u);
    const size_t qo = ((size_t)b * 243 + t) * 1024 + h * 64;
    const size_t kvb = (size_t)b * 77 * 1024 + h * 64;
    float p[77];
    float mx = -1e30f;
    for (int n = 0; n < 77; ++n) {
        const size_t ko = kvb + (size_t)n * 1024;
        float acc = 0.f;
        for (int d = 0; d < 64; ++d) acc += b2f(Q[qo + d]) * b2f(K_[ko + d]);
        p[n] = acc * 0.125f;
        mx = fmaxf(mx, p[n]);
    }
    float ss = 0.f;
    for (int n = 0; n < 77; ++n) { p[n] = __expf(p[n] - mx); ss += p[n]; }
    const float inv = 1.f / ss;
    int bad = 0;
    for (unsigned j = 0; j < 4; ++j) {
        const int d = (int)((s * 13u + j * 17u) % 64u);
        float acc = 0.f;
        for (int n = 0; n < 77; ++n) acc += p[n] * b2f(V[kvb + (size_t)n * 1024 + d]);
        if (!(fabsf(b2f(Y[qo + d]) - acc * inv) <= 0.05f)) bad = 1;
    }
    if (bad) atomicOr(flag, 1);
}

// flag-gated scalar attention fallback (round-7 proven semantics)
__global__ __launch_bounds__(256) void k_attn_fb(const unsigned short* __restrict__ Q,
                                                 const unsigned short* __restrict__ K_,
                                                 const unsigned short* __restrict__ V,
                                                 unsigned short* __restrict__ Y,
                                                 const int* __restrict__ flag) {
    if (*flag == 0) return;
    for (int idx = blockIdx.x * 256 + threadIdx.x; idx < 128 * 243 * 16; idx += gridDim.x * 256) {
        const int b = idx / (243 * 16);
        const int r = idx - b * (243 * 16);
        const int t = r >> 4, h = r & 15;
        const size_t qo = ((size_t)b * 243 + t) * 1024 + h * 64;
        const size_t kvb = (size_t)b * 77 * 1024 + h * 64;
        float p[77];
        float mx = -1e30f;
        for (int n = 0; n < 77; ++n) {
            const size_t ko = kvb + (size_t)n * 1024;
            float acc = 0.f;
            for (int d = 0; d < 64; ++d) acc += b2f(Q[qo + d]) * b2f(K_[ko + d]);
            p[n] = acc * 0.125f;
            mx = fmaxf(mx, p[n]);
        }
        float ss = 0.f;
        for (int n = 0; n < 77; ++n) { p[n] = __expf(p[n] - mx); ss += p[n]; }
        const float inv = 1.f / ss;
        for (int dc = 0; dc < 8; ++dc) {
            float ya[8] = {0.f, 0.f, 0.f, 0.f, 0.f, 0.f, 0.f, 0.f};
            for (int n = 0; n < 77; ++n) {
                const float pv = p[n];
                const size_t vo = kvb + (size_t)n * 1024 + dc * 8;
#pragma unroll
                for (int j = 0; j < 8; ++j) ya[j] += pv * b2f(V[vo + j]);
            }
#pragma unroll
            for (int j = 0; j < 8; ++j) Y[qo + dc * 8 + j] = f2b(ya[j] * inv);
        }
    }
}

// ---------------------------------------------------------------------------
// Stylization [validated]
// ---------------------------------------------------------------------------
__global__ __launch_bounds__(256) void k_act(const unsigned short* __restrict__ y,
                                             const float* __restrict__ eo,
                                             const float* __restrict__ g,
                                             const float* __restrict__ b,
                                             unsigned short* __restrict__ out) {
    const int row = blockIdx.x * 4 + (threadIdx.x >> 6);
    const int ln = threadIdx.x & 63;
    const int bb = row / 243;
    float v[16];
    const size_t base = (size_t)row * 1024 + ln * 16;
#pragma unroll
    for (int c = 0; c < 16; ++c) v[c] = b2f(y[base + c]);
    float s = 0.f, s2 = 0.f;
#pragma unroll
    for (int c = 0; c < 16; ++c) { s += v[c]; s2 += v[c] * v[c]; }
    for (int o = 1; o < 64; o <<= 1) { s += __shfl_xor(s, o); s2 += __shfl_xor(s2, o); }
    const float mean = s / 1024.f;
    const float rstd = rsqrtf(s2 / 1024.f - mean * mean + 1e-5f);
#pragma unroll
    for (int c = 0; c < 16; ++c) {
        const int kk = ln * 16 + c;
        const float nl = (v[c] - mean) * rstd * g[kk] + b[kk];
        const float hh = nl * (1.f + eo[(size_t)bb * 2048 + kk]) + eo[(size_t)bb * 2048 + 1024 + kk];
        out[base + c] = f2b(hh / (1.f + __expf(-hh)));
    }
}

// ---------------------------------------------------------------------------
extern "C" void kernel_launch(void* const* d_in, const int* in_sizes, int n_in,
                              void* d_out, int out_size, void* d_ws, size_t ws_size,
                              hipStream_t stream) {
    (void)in_sizes; (void)n_in; (void)out_size; (void)ws_size;

    const float* x     = (const float*)d_in[0];
    const float* xf    = (const float*)d_in[1];
    const float* emb   = (const float*)d_in[2];
    const float* ln_g  = (const float*)d_in[3];
    const float* ln_b  = (const float*)d_in[4];
    const float* tln_g = (const float*)d_in[5];
    const float* tln_b = (const float*)d_in[6];
    const float* Wq    = (const float*)d_in[7];
    const float* bq    = (const float*)d_in[8];
    const float* Wk    = (const float*)d_in[9];
    const float* bk    = (const float*)d_in[10];
    const float* Wv    = (const float*)d_in[11];
    const float* bv    = (const float*)d_in[12];
    const float* We    = (const float*)d_in[13];
    const float* be    = (const float*)d_in[14];
    const float* ln2_g = (const float*)d_in[15];
    const float* ln2_b = (const float*)d_in[16];
    const float* Wo    = (const float*)d_in[17];
    const float* bo    = (const float*)d_in[18];
    float* outp = (float*)d_out;

    char* ws = (char*)d_ws;
    constexpr size_t o_wq   = 0;
    constexpr size_t o_wkv  = o_wq + 2097152;
    constexpr size_t o_we   = o_wkv + 2097152;
    constexpr size_t o_wo   = o_we + 4194304;
    constexpr size_t o_se   = o_wo + 2097152;
    constexpr size_t o_eo   = o_se + 262144;
    constexpr size_t o_flag = o_eo + 1048576;
    constexpr size_t o_xn   = o_flag + 256;
    constexpr size_t o_qb   = o_xn + 63700992;
    constexpr size_t o_xfn  = o_qb + 63700992;
    constexpr size_t o_kb   = o_xfn + 10092544;
    constexpr size_t o_vb   = o_kb + 20185088;

    unsigned short* wqt  = (unsigned short*)(ws + o_wq);
    unsigned short* wkvt = (unsigned short*)(ws + o_wkv);
    unsigned short* wet  = (unsigned short*)(ws + o_we);
    unsigned short* wot  = (unsigned short*)(ws + o_wo);
    unsigned short* se   = (unsigned short*)(ws + o_se);
    float*          eo   = (float*)(ws + o_eo);
    int*            flg  = (int*)(ws + o_flag);
    unsigned short* xn   = (unsigned short*)(ws + o_xn);
    unsigned short* yb   = xn;
    unsigned short* qb   = (unsigned short*)(ws + o_qb);
    unsigned short* actb = qb;
    unsigned short* xfn  = (unsigned short*)(ws + o_xfn);
    unsigned short* kb   = (unsigned short*)(ws + o_kb);
    unsigned short* vb   = (unsigned short*)(ws + o_vb);

    k_zero<<<1, 64, 0, stream>>>(flg);

    // pre-passes
    k_ln<1024><<<7776, 256, 0, stream>>>(x, ln_g, ln_b, xn);
    k_ln<512><<<2464, 256, 0, stream>>>(xf, tln_g, tln_b, xfn);
    k_silu<<<512, 256, 0, stream>>>(emb, se);
    k_cvt<<<dim3(32, 32), 256, 0, stream>>>(Wq, wqt, 1024, 1024);
    k_cvt<<<dim3(32, 16), 256, 0, stream>>>(Wk, wkvt, 512, 1024);
    k_cvt<<<dim3(32, 16), 256, 0, stream>>>(Wv, wkvt + 1024 * 512, 512, 1024);
    k_cvt<<<dim3(64, 32), 256, 0, stream>>>(We, wet, 1024, 2048);
    k_cvt<<<dim3(32, 32), 256, 0, stream>>>(Wo, wot, 1024, 1024);

    // eo = silu(emb0) @ We + be
    k_mm<3><<<dim3(1, 16), 256, 0, stream>>>(se, wet, be, nullptr,
                                             nullptr, nullptr, eo, nullptr, 2048, 1024);
    k_vmm<1><<<1, 256, 0, stream>>>(se, wet, be, nullptr, eo, nullptr,
                                    128, 2048, 1024, 0.05f, flg + 3);
    k_gnf_fb<<<1024, 256, 0, stream>>>(se, We, be, eo, 262144L, 2048, 1024, flg + 3);

    // Q projection
    k_mm<0><<<dim3(243, 8), 256, 0, stream>>>(xn, wqt, bq, nullptr,
                                              qb, nullptr, nullptr, nullptr, 1024, 1024);
    k_vmm<0><<<1, 256, 0, stream>>>(xn, wqt, bq, qb, nullptr, nullptr,
                                    31104, 1024, 1024, 0.1f, flg + 0);
    k_gn_fb<<<2048, 256, 0, stream>>>(xn, Wq, bq, qb, 31850496L, 1024, 1024, flg + 0);

    // KV projection
    k_mm<2><<<dim3(77, 16), 256, 0, stream>>>(xfn, wkvt, bk, bv,
                                              kb, vb, nullptr, nullptr, 2048, 512);
    k_vmm<0><<<1, 256, 0, stream>>>(xfn, wkvt, bk, kb, nullptr, nullptr,
                                    9856, 1024, 512, 0.1f, flg + 1);
    k_vmm<0><<<1, 256, 0, stream>>>(xfn, wkvt + 1024 * 512, bv, vb, nullptr, nullptr,
                                    9856, 1024, 512, 0.1f, flg + 2);
    k_gn_fb<<<2048, 256, 0, stream>>>(xfn, Wk, bk, kb, 10092544L, 1024, 512, flg + 1);
    k_gn_fb<<<2048, 256, 0, stream>>>(xfn, Wv, bv, vb, 10092544L, 1024, 512, flg + 2);

    // attention: MFMA + verify + flag-gated scalar fallback
    k_attn_m<<<2048, 256, 0, stream>>>(qb, kb, vb, yb);
    k_vattn<<<1, 64, 0, stream>>>(qb, kb, vb, yb, flg + 5);
    k_attn_fb<<<1944, 256, 0, stream>>>(qb, kb, vb, yb, flg + 5);

    // stylization
    k_act<<<7776, 256, 0, stream>>>(yb, eo, ln2_g, ln2_b, actb);

    // output projection + residual -> d_out
    k_mm<1><<<dim3(243, 8), 256, 0, stream>>>(actb, wot, bo, nullptr,
                                              nullptr, nullptr, outp, x, 1024, 1024);
    k_vmm<2><<<1, 256, 0, stream>>>(actb, wot, bo, nullptr, outp, x,
                                    31104, 1024, 1024, 0.05f, flg + 4);
    k_gno_fb<<<2048, 256, 0, stream>>>(actb, Wo, bo, x, outp, 31850496L, 1024, 1024, flg + 4);
}

// Round 10
// 1107.433 us; speedup vs baseline: 20.0024x; 2.8250x over previous
//
#include <hip/hip_runtime.h>
#include <cstdint>

typedef __attribute__((ext_vector_type(8))) __bf16 bf16x8;
typedef __attribute__((ext_vector_type(4))) float f32x4;

__device__ __forceinline__ float b2f(unsigned short u) {
    union { uint32_t i; float f; } w; w.i = ((uint32_t)u) << 16; return w.f;
}
__device__ __forceinline__ unsigned short f2b(float f) {
    union { uint32_t i; float f; } w; w.f = f;
    uint32_t r = (w.i + 0x7FFFu + ((w.i >> 16) & 1u)) >> 16;
    return (unsigned short)r;
}

// ---------------------------------------------------------------------------
// Weight convert+transpose: W f32 (R x C) -> Wt bf16 (C x R)
// ---------------------------------------------------------------------------
__global__ __launch_bounds__(256) void k_cvt(const float* __restrict__ in,
                                             unsigned short* __restrict__ out,
                                             int R, int C) {
    __shared__ float s[32][33];
    const int c0 = blockIdx.x * 32, r0 = blockIdx.y * 32;
    const int tx = threadIdx.x & 31, ty = threadIdx.x >> 5;
#pragma unroll
    for (int i = 0; i < 4; ++i)
        s[ty + i * 8][tx] = in[(size_t)(r0 + ty + i * 8) * C + c0 + tx];
    __syncthreads();
#pragma unroll
    for (int i = 0; i < 4; ++i)
        out[(size_t)(c0 + ty + i * 8) * R + r0 + tx] = f2b(s[tx][ty + i * 8]);
}

// ---------------------------------------------------------------------------
// LayerNorm f32 -> bf16, one wave per row
// ---------------------------------------------------------------------------
template <int DIM>
__global__ __launch_bounds__(256) void k_ln(const float* __restrict__ in,
                                            const float* __restrict__ g,
                                            const float* __restrict__ b,
                                            unsigned short* __restrict__ out) {
    const int row = blockIdx.x * 4 + (threadIdx.x >> 6);
    const int ln = threadIdx.x & 63;
    constexpr int PL = DIM / 64;
    float v[PL];
    const size_t base = (size_t)row * DIM + (size_t)ln * PL;
#pragma unroll
    for (int c = 0; c < PL; ++c) v[c] = in[base + c];
    float s = 0.f, s2 = 0.f;
#pragma unroll
    for (int c = 0; c < PL; ++c) { s += v[c]; s2 += v[c] * v[c]; }
    for (int o = 1; o < 64; o <<= 1) { s += __shfl_xor(s, o); s2 += __shfl_xor(s2, o); }
    const float mean = s / DIM;
    const float rstd = rsqrtf(s2 / DIM - mean * mean + 1e-5f);
#pragma unroll
    for (int c = 0; c < PL; ++c) {
        const int kk = ln * PL + c;
        out[(size_t)row * DIM + kk] = f2b((v[c] - mean) * rstd * g[kk] + b[kk]);
    }
}

__global__ __launch_bounds__(256) void k_silu(const float* __restrict__ emb,
                                              unsigned short* __restrict__ se) {
    const int i = blockIdx.x * 256 + threadIdx.x;
    const int b = i >> 10, k = i & 1023;
    const float f = emb[(size_t)b * (243 * 1024) + k];
    se[i] = f2b(f / (1.f + __expf(-f)));
}

// ---------------------------------------------------------------------------
// MFMA GEMM (HW-validated r8/r9): C = A[M,K](bf16) @ Bt[N,K]^T(bf16); bias f32.
// EPI 0: C0 bf16 | EPI 1: Cf f32 = acc+bias+X | EPI 2: KV split | EPI 3: Cf f32
// ---------------------------------------------------------------------------
template <int EPI>
__global__ __launch_bounds__(256, 2) void k_mm(
    const unsigned short* __restrict__ A, const unsigned short* __restrict__ Bt,
    const float* __restrict__ bias0, const float* __restrict__ bias1,
    unsigned short* __restrict__ C0, unsigned short* __restrict__ C1,
    float* __restrict__ Cf, const float* __restrict__ X,
    int N, int K) {
    __shared__ __align__(16) unsigned short sA[128 * 64];
    __shared__ __align__(16) unsigned short sB[128 * 64];
    const int tid = threadIdx.x, wv = tid >> 6, ln = tid & 63;
    const int wm = wv >> 1, wn = wv & 1;
    const int ln15 = ln & 15, lg = ln >> 4;
    const int m0 = blockIdx.x * 128, n0 = blockIdx.y * 128;

    const f32x4 fz = {0.f, 0.f, 0.f, 0.f};
    f32x4 acc[4][4];
#pragma unroll
    for (int i = 0; i < 4; ++i)
#pragma unroll
        for (int j = 0; j < 4; ++j) acc[i][j] = fz;

    const int lrow = ln >> 3;
    const int lslot = ln & 7;
    const unsigned short* ga = A + (size_t)(m0 + wv * 32 + lrow) * K + lslot * 8;
    const unsigned short* gb = Bt + (size_t)(n0 + wv * 32 + lrow) * K + lslot * 8;
    char* const wA = (char*)sA + (wv * 32 + lrow) * 128 + ((lslot ^ lrow) * 16);
    char* const wB = (char*)sB + (wv * 32 + lrow) * 128 + ((lslot ^ lrow) * 16);

    for (int k0 = 0; k0 < K; k0 += 64) {
        uint4 ra[4], rb[4];
#pragma unroll
        for (int i = 0; i < 4; ++i) {
            ra[i] = *(const uint4*)(ga + k0 + (size_t)i * 8 * K);
            rb[i] = *(const uint4*)(gb + k0 + (size_t)i * 8 * K);
        }
        __syncthreads();
#pragma unroll
        for (int i = 0; i < 4; ++i) {
            *(uint4*)(wA + i * 8 * 128) = ra[i];
            *(uint4*)(wB + i * 8 * 128) = rb[i];
        }
        __syncthreads();
        bf16x8 af[4][2], bf[4][2];
#pragma unroll
        for (int i = 0; i < 4; ++i) {
            const int ra2 = wm * 64 + i * 16 + ln15;
            const int rb2 = wn * 64 + i * 16 + ln15;
#pragma unroll
            for (int ks = 0; ks < 2; ++ks) {
                const int slot = ks * 4 + lg;
                af[i][ks] = *(const bf16x8*)(sA + ra2 * 64 + ((slot ^ (ra2 & 7)) * 8));
                bf[i][ks] = *(const bf16x8*)(sB + rb2 * 64 + ((slot ^ (rb2 & 7)) * 8));
            }
        }
#pragma unroll
        for (int mi = 0; mi < 4; ++mi)
#pragma unroll
            for (int ni = 0; ni < 4; ++ni) {
                acc[mi][ni] = __builtin_amdgcn_mfma_f32_16x16x32_bf16(af[mi][0], bf[ni][0], acc[mi][ni], 0, 0, 0);
                acc[mi][ni] = __builtin_amdgcn_mfma_f32_16x16x32_bf16(af[mi][1], bf[ni][1], acc[mi][ni], 0, 0, 0);
            }
    }

    const int colB = n0 + wn * 64;
    const int rowB = m0 + wm * 64;
#pragma unroll
    for (int mi = 0; mi < 4; ++mi) {
#pragma unroll
        for (int ni = 0; ni < 4; ++ni) {
            const int col = colB + ni * 16 + ln15;
            const int row = rowB + mi * 16 + lg * 4;
            float bvv;
            if (EPI == 2) bvv = (col < 1024) ? bias0[col] : bias1[col - 1024];
            else bvv = bias0[col];
#pragma unroll
            for (int r = 0; r < 4; ++r) {
                const float v = acc[mi][ni][r] + bvv;
                if (EPI == 0) {
                    C0[(size_t)(row + r) * N + col] = f2b(v);
                } else if (EPI == 1) {
                    Cf[(size_t)(row + r) * N + col] = v + X[(size_t)(row + r) * N + col];
                } else if (EPI == 2) {
                    if (col < 1024) C0[(size_t)(row + r) * 1024 + col] = f2b(v);
                    else C1[(size_t)(row + r) * 1024 + (col - 1024)] = f2b(v);
                } else {
                    Cf[(size_t)(row + r) * N + col] = v;
                }
            }
        }
    }
}

// ---------------------------------------------------------------------------
// MFMA cross-attention (HW-validated r9): one block per (b,h)
// ---------------------------------------------------------------------------
__global__ __launch_bounds__(256, 2) void k_attn_m(const unsigned short* __restrict__ Q,
                                                   const unsigned short* __restrict__ Kb,
                                                   const unsigned short* __restrict__ Vb,
                                                   unsigned short* __restrict__ Y) {
    __shared__ __align__(16) unsigned short sK[80 * 64];
    __shared__ __align__(16) unsigned short sV[64 * 96];
    __shared__ __align__(16) unsigned short sP[4][16 * 104];
    const int bh = blockIdx.x;
    const int b = bh >> 4, h = bh & 15;
    const int tid = threadIdx.x, wv = tid >> 6, ln = tid & 63;
    const int ln15 = ln & 15, lg = ln >> 4;

    for (int c = tid; c < 640; c += 256) {
        const int n = c >> 3, ci = c & 7;
        uint4 val = make_uint4(0u, 0u, 0u, 0u);
        if (n < 77) val = *(const uint4*)(Kb + (size_t)(b * 77 + n) * 1024 + h * 64 + ci * 8);
        *(uint4*)((char*)sK + n * 128 + ((ci * 16) ^ ((n & 7) << 4))) = val;
    }
    for (int i = tid; i < 64 * 96; i += 256) {
        const int d = i / 96, n = i - d * 96;
        unsigned short val = 0;
        if (n < 77) val = Vb[(size_t)(b * 77 + n) * 1024 + h * 64 + d];
        sV[i] = val;
    }
    for (int i = ln; i < 16 * 24; i += 64) {
        const int rr = i / 24, cc = i - rr * 24;
        sP[wv][rr * 104 + 80 + cc] = 0;
    }
    bf16x8 qf[4][2];
    const size_t qbase = (size_t)b * (243 * 1024) + h * 64;
#pragma unroll
    for (int mi = 0; mi < 4; ++mi) {
        int t = wv * 64 + mi * 16 + ln15;
        if (t > 242) t = 242;
#pragma unroll
        for (int ks = 0; ks < 2; ++ks)
            qf[mi][ks] = *(const bf16x8*)(Q + qbase + (size_t)t * 1024 + ks * 32 + lg * 8);
    }
    __syncthreads();

    const f32x4 fz = {0.f, 0.f, 0.f, 0.f};
    f32x4 yacc[4][4];
#pragma unroll
    for (int i = 0; i < 4; ++i)
#pragma unroll
        for (int j = 0; j < 4; ++j) yacc[i][j] = fz;

#pragma unroll
    for (int mi = 0; mi < 4; ++mi) {
        f32x4 sc[5];
#pragma unroll
        for (int ci = 0; ci < 5; ++ci) sc[ci] = fz;
#pragma unroll
        for (int ci = 0; ci < 5; ++ci) {
            const int n = ci * 16 + ln15;
#pragma unroll
            for (int ks = 0; ks < 2; ++ks) {
                const int kk = ks * 32 + lg * 8;
                bf16x8 kf = *(const bf16x8*)((const char*)sK + n * 128 + ((kk * 2) ^ ((n & 7) << 4)));
                sc[ci] = __builtin_amdgcn_mfma_f32_16x16x32_bf16(qf[mi][ks], kf, sc[ci], 0, 0, 0);
            }
        }
#pragma unroll
        for (int r = 0; r < 4; ++r) {
            float e[5];
            float mx = -1e30f;
#pragma unroll
            for (int ci = 0; ci < 5; ++ci) {
                const int n = ci * 16 + ln15;
                const float vv = (n < 77) ? sc[ci][r] * 0.125f : -1e30f;
                e[ci] = vv;
                mx = fmaxf(mx, vv);
            }
            mx = fmaxf(mx, __shfl_xor(mx, 1));
            mx = fmaxf(mx, __shfl_xor(mx, 2));
            mx = fmaxf(mx, __shfl_xor(mx, 4));
            mx = fmaxf(mx, __shfl_xor(mx, 8));
            float ssum = 0.f;
#pragma unroll
            for (int ci = 0; ci < 5; ++ci) {
                const int n = ci * 16 + ln15;
                const float ev = (n < 77) ? __expf(e[ci] - mx) : 0.f;
                e[ci] = ev;
                ssum += ev;
            }
            ssum += __shfl_xor(ssum, 1);
            ssum += __shfl_xor(ssum, 2);
            ssum += __shfl_xor(ssum, 4);
            ssum += __shfl_xor(ssum, 8);
            const float inv = 1.f / ssum;
            const int prow = lg * 4 + r;
#pragma unroll
            for (int ci = 0; ci < 5; ++ci)
                sP[wv][prow * 104 + ci * 16 + ln15] = f2b(e[ci] * inv);
        }
        __syncthreads();
#pragma unroll
        for (int ks = 0; ks < 3; ++ks) {
            bf16x8 pa = *(const bf16x8*)(sP[wv] + ln15 * 104 + ks * 32 + lg * 8);
#pragma unroll
            for (int di = 0; di < 4; ++di) {
                bf16x8 vf = *(const bf16x8*)(sV + (di * 16 + ln15) * 96 + ks * 32 + lg * 8);
                yacc[mi][di] = __builtin_amdgcn_mfma_f32_16x16x32_bf16(pa, vf, yacc[mi][di], 0, 0, 0);
            }
        }
        __syncthreads();
    }
    const size_t ybase = (size_t)b * (243 * 1024) + h * 64;
#pragma unroll
    for (int mi = 0; mi < 4; ++mi)
#pragma unroll
        for (int di = 0; di < 4; ++di)
#pragma unroll
            for (int r = 0; r < 4; ++r) {
                const int t = wv * 64 + mi * 16 + lg * 4 + r;
                if (t < 243) Y[ybase + (size_t)t * 1024 + di * 16 + ln15] = f2b(yacc[mi][di][r]);
            }
}

// ---------------------------------------------------------------------------
// Stylization (HW-validated)
// ---------------------------------------------------------------------------
__global__ __launch_bounds__(256) void k_act(const unsigned short* __restrict__ y,
                                             const float* __restrict__ eo,
                                             const float* __restrict__ g,
                                             const float* __restrict__ b,
                                             unsigned short* __restrict__ out) {
    const int row = blockIdx.x * 4 + (threadIdx.x >> 6);
    const int ln = threadIdx.x & 63;
    const int bb = row / 243;
    float v[16];
    const size_t base = (size_t)row * 1024 + ln * 16;
#pragma unroll
    for (int c = 0; c < 16; ++c) v[c] = b2f(y[base + c]);
    float s = 0.f, s2 = 0.f;
#pragma unroll
    for (int c = 0; c < 16; ++c) { s += v[c]; s2 += v[c] * v[c]; }
    for (int o = 1; o < 64; o <<= 1) { s += __shfl_xor(s, o); s2 += __shfl_xor(s2, o); }
    const float mean = s / 1024.f;
    const float rstd = rsqrtf(s2 / 1024.f - mean * mean + 1e-5f);
#pragma unroll
    for (int c = 0; c < 16; ++c) {
        const int kk = ln * 16 + c;
        const float nl = (v[c] - mean) * rstd * g[kk] + b[kk];
        const float hh = nl * (1.f + eo[(size_t)bb * 2048 + kk]) + eo[(size_t)bb * 2048 + 1024 + kk];
        out[base + c] = f2b(hh / (1.f + __expf(-hh)));
    }
}

// ---------------------------------------------------------------------------
extern "C" void kernel_launch(void* const* d_in, const int* in_sizes, int n_in,
                              void* d_out, int out_size, void* d_ws, size_t ws_size,
                              hipStream_t stream) {
    (void)in_sizes; (void)n_in; (void)out_size; (void)ws_size;

    const float* x     = (const float*)d_in[0];
    const float* xf    = (const float*)d_in[1];
    const float* emb   = (const float*)d_in[2];
    const float* ln_g  = (const float*)d_in[3];
    const float* ln_b  = (const float*)d_in[4];
    const float* tln_g = (const float*)d_in[5];
    const float* tln_b = (const float*)d_in[6];
    const float* Wq    = (const float*)d_in[7];
    const float* bq    = (const float*)d_in[8];
    const float* Wk    = (const float*)d_in[9];
    const float* bk    = (const float*)d_in[10];
    const float* Wv    = (const float*)d_in[11];
    const float* bv    = (const float*)d_in[12];
    const float* We    = (const float*)d_in[13];
    const float* be    = (const float*)d_in[14];
    const float* ln2_g = (const float*)d_in[15];
    const float* ln2_b = (const float*)d_in[16];
    const float* Wo    = (const float*)d_in[17];
    const float* bo    = (const float*)d_in[18];
    float* outp = (float*)d_out;

    char* ws = (char*)d_ws;
    constexpr size_t o_wq   = 0;
    constexpr size_t o_wkv  = o_wq + 2097152;
    constexpr size_t o_we   = o_wkv + 2097152;
    constexpr size_t o_wo   = o_we + 4194304;
    constexpr size_t o_se   = o_wo + 2097152;
    constexpr size_t o_eo   = o_se + 262144;
    constexpr size_t o_xn   = o_eo + 1048576;
    constexpr size_t o_qb   = o_xn + 63700992;
    constexpr size_t o_xfn  = o_qb + 63700992;
    constexpr size_t o_kb   = o_xfn + 10092544;
    constexpr size_t o_vb   = o_kb + 20185088;

    unsigned short* wqt  = (unsigned short*)(ws + o_wq);
    unsigned short* wkvt = (unsigned short*)(ws + o_wkv);
    unsigned short* wet  = (unsigned short*)(ws + o_we);
    unsigned short* wot  = (unsigned short*)(ws + o_wo);
    unsigned short* se   = (unsigned short*)(ws + o_se);
    float*          eo   = (float*)(ws + o_eo);
    unsigned short* xn   = (unsigned short*)(ws + o_xn);
    unsigned short* yb   = xn;                      // alias: xn dead after Q-GEMM
    unsigned short* qb   = (unsigned short*)(ws + o_qb);
    unsigned short* actb = qb;                      // alias: q dead after attention
    unsigned short* xfn  = (unsigned short*)(ws + o_xfn);
    unsigned short* kb   = (unsigned short*)(ws + o_kb);
    unsigned short* vb   = (unsigned short*)(ws + o_vb);

    // pre-passes
    k_ln<1024><<<7776, 256, 0, stream>>>(x, ln_g, ln_b, xn);
    k_ln<512><<<2464, 256, 0, stream>>>(xf, tln_g, tln_b, xfn);
    k_silu<<<512, 256, 0, stream>>>(emb, se);
    k_cvt<<<dim3(32, 32), 256, 0, stream>>>(Wq, wqt, 1024, 1024);
    k_cvt<<<dim3(32, 16), 256, 0, stream>>>(Wk, wkvt, 512, 1024);
    k_cvt<<<dim3(32, 16), 256, 0, stream>>>(Wv, wkvt + 1024 * 512, 512, 1024);
    k_cvt<<<dim3(64, 32), 256, 0, stream>>>(We, wet, 1024, 2048);
    k_cvt<<<dim3(32, 32), 256, 0, stream>>>(Wo, wot, 1024, 1024);

    // eo = silu(emb0) @ We + be  (f32 out)
    k_mm<3><<<dim3(1, 16), 256, 0, stream>>>(se, wet, be, nullptr,
                                             nullptr, nullptr, eo, nullptr, 2048, 1024);

    // projections
    k_mm<0><<<dim3(243, 8), 256, 0, stream>>>(xn, wqt, bq, nullptr,
                                              qb, nullptr, nullptr, nullptr, 1024, 1024);
    k_mm<2><<<dim3(77, 16), 256, 0, stream>>>(xfn, wkvt, bk, bv,
                                              kb, vb, nullptr, nullptr, 2048, 512);

    // attention
    k_attn_m<<<2048, 256, 0, stream>>>(qb, kb, vb, yb);

    // stylization
    k_act<<<7776, 256, 0, stream>>>(yb, eo, ln2_g, ln2_b, actb);

    // output projection + residual -> d_out (f32)
    k_mm<1><<<dim3(243, 8), 256, 0, stream>>>(actb, wot, bo, nullptr,
                                              nullptr, nullptr, outp, x, 1024, 1024);
}

// Round 11
// 449.211 us; speedup vs baseline: 49.3117x; 2.4653x over previous
//
#include <hip/hip_runtime.h>
#include <cstdint>

typedef __attribute__((ext_vector_type(8))) __bf16 bf16x8;
typedef __attribute__((ext_vector_type(4))) float f32x4;

__device__ __forceinline__ float b2f(unsigned short u) {
    union { uint32_t i; float f; } w; w.i = ((uint32_t)u) << 16; return w.f;
}
__device__ __forceinline__ unsigned short f2b(float f) {
    union { uint32_t i; float f; } w; w.f = f;
    uint32_t r = (w.i + 0x7FFFu + ((w.i >> 16) & 1u)) >> 16;
    return (unsigned short)r;
}

// 16B global -> LDS direct (wave-uniform LDS base; HW adds lane*16).
// Clean addrspace casts (compiler emits addrspacecast, no integer truncation).
__device__ __forceinline__ void gl16(const unsigned short* g, unsigned short* l) {
    __builtin_amdgcn_global_load_lds(
        (const __attribute__((address_space(1))) void*)g,
        (__attribute__((address_space(3))) void*)l,
        16, 0, 0);
}

// ---------------------------------------------------------------------------
// Weight convert+transpose: W f32 (R x C) -> Wt bf16 (C x R)
// ---------------------------------------------------------------------------
__global__ __launch_bounds__(256) void k_cvt(const float* __restrict__ in,
                                             unsigned short* __restrict__ out,
                                             int R, int C) {
    __shared__ float s[32][33];
    const int c0 = blockIdx.x * 32, r0 = blockIdx.y * 32;
    const int tx = threadIdx.x & 31, ty = threadIdx.x >> 5;
#pragma unroll
    for (int i = 0; i < 4; ++i)
        s[ty + i * 8][tx] = in[(size_t)(r0 + ty + i * 8) * C + c0 + tx];
    __syncthreads();
#pragma unroll
    for (int i = 0; i < 4; ++i)
        out[(size_t)(c0 + ty + i * 8) * R + r0 + tx] = f2b(s[tx][ty + i * 8]);
}

// ---------------------------------------------------------------------------
// LayerNorm f32 -> bf16, one wave per row
// ---------------------------------------------------------------------------
template <int DIM>
__global__ __launch_bounds__(256) void k_ln(const float* __restrict__ in,
                                            const float* __restrict__ g,
                                            const float* __restrict__ b,
                                            unsigned short* __restrict__ out) {
    const int row = blockIdx.x * 4 + (threadIdx.x >> 6);
    const int ln = threadIdx.x & 63;
    constexpr int PL = DIM / 64;
    float v[PL];
    const size_t base = (size_t)row * DIM + (size_t)ln * PL;
#pragma unroll
    for (int c = 0; c < PL; ++c) v[c] = in[base + c];
    float s = 0.f, s2 = 0.f;
#pragma unroll
    for (int c = 0; c < PL; ++c) { s += v[c]; s2 += v[c] * v[c]; }
    for (int o = 1; o < 64; o <<= 1) { s += __shfl_xor(s, o); s2 += __shfl_xor(s2, o); }
    const float mean = s / DIM;
    const float rstd = rsqrtf(s2 / DIM - mean * mean + 1e-5f);
#pragma unroll
    for (int c = 0; c < PL; ++c) {
        const int kk = ln * PL + c;
        out[(size_t)row * DIM + kk] = f2b((v[c] - mean) * rstd * g[kk] + b[kk]);
    }
}

__global__ __launch_bounds__(256) void k_silu(const float* __restrict__ emb,
                                              unsigned short* __restrict__ se) {
    const int i = blockIdx.x * 256 + threadIdx.x;
    const int b = i >> 10, k = i & 1023;
    const float f = emb[(size_t)b * (243 * 1024) + k];
    se[i] = f2b(f / (1.f + __expf(-f)));
}

// ---------------------------------------------------------------------------
// MFMA GEMM, m97-structure: global_load_lds width-16 staging, 2 barriers/K-step.
// Pre-swizzled global source + linear LDS dest + XOR-swizzled ds_read (rule 21).
// LDS contents identical to the r8/r9-validated reg-staged version:
//   LDS[r][s] = G[r][s ^ (r&7)]  -> fragment reads unchanged.
// EPI 0: C0 bf16 | EPI 1: Cf f32 = acc+bias+X | EPI 2: KV split | EPI 3: Cf f32
// ---------------------------------------------------------------------------
template <int EPI>
__global__ __launch_bounds__(256, 2) void k_mm(
    const unsigned short* __restrict__ A, const unsigned short* __restrict__ Bt,
    const float* __restrict__ bias0, const float* __restrict__ bias1,
    unsigned short* __restrict__ C0, unsigned short* __restrict__ C1,
    float* __restrict__ Cf, const float* __restrict__ X,
    int N, int K) {
    __shared__ __align__(16) unsigned short sA[128 * 64];
    __shared__ __align__(16) unsigned short sB[128 * 64];
    const int tid = threadIdx.x, wv = tid >> 6, ln = tid & 63;
    const int wm = wv >> 1, wn = wv & 1;
    const int ln15 = ln & 15, lg = ln >> 4;
    const int m0 = blockIdx.x * 128, n0 = blockIdx.y * 128;

    const f32x4 fz = {0.f, 0.f, 0.f, 0.f};
    f32x4 acc[4][4];
#pragma unroll
    for (int i = 0; i < 4; ++i)
#pragma unroll
        for (int j = 0; j < 4; ++j) acc[i][j] = fz;

    const int lrow = ln >> 3;                  // 0..7: row within 8-row chunk
    const int sslot = (ln & 7) ^ lrow;         // pre-swizzled global 16B slot
    const unsigned short* ga = A + (size_t)(m0 + wv * 32 + lrow) * K + sslot * 8;
    const unsigned short* gb = Bt + (size_t)(n0 + wv * 32 + lrow) * K + sslot * 8;
    unsigned short* const lA = sA + (wv * 32) * 64;   // wave-uniform LDS bases
    unsigned short* const lB = sB + (wv * 32) * 64;

    for (int k0 = 0; k0 < K; k0 += 64) {
#pragma unroll
        for (int i = 0; i < 4; ++i) {
            gl16(ga + k0 + (size_t)i * 8 * K, lA + i * 8 * 64);
            gl16(gb + k0 + (size_t)i * 8 * K, lB + i * 8 * 64);
        }
        __syncthreads();   // vmcnt drained before barrier -> tile resident
        bf16x8 af[4][2], bf[4][2];
#pragma unroll
        for (int i = 0; i < 4; ++i) {
            const int ra2 = wm * 64 + i * 16 + ln15;
            const int rb2 = wn * 64 + i * 16 + ln15;
#pragma unroll
            for (int ks = 0; ks < 2; ++ks) {
                const int slot = ks * 4 + lg;
                af[i][ks] = *(const bf16x8*)(sA + ra2 * 64 + ((slot ^ (ra2 & 7)) * 8));
                bf[i][ks] = *(const bf16x8*)(sB + rb2 * 64 + ((slot ^ (rb2 & 7)) * 8));
            }
        }
#pragma unroll
        for (int mi = 0; mi < 4; ++mi)
#pragma unroll
            for (int ni = 0; ni < 4; ++ni) {
                acc[mi][ni] = __builtin_amdgcn_mfma_f32_16x16x32_bf16(af[mi][0], bf[ni][0], acc[mi][ni], 0, 0, 0);
                acc[mi][ni] = __builtin_amdgcn_mfma_f32_16x16x32_bf16(af[mi][1], bf[ni][1], acc[mi][ni], 0, 0, 0);
            }
        __syncthreads();   // protect LDS from next stage
    }

    const int colB = n0 + wn * 64;
    const int rowB = m0 + wm * 64;
#pragma unroll
    for (int mi = 0; mi < 4; ++mi) {
#pragma unroll
        for (int ni = 0; ni < 4; ++ni) {
            const int col = colB + ni * 16 + ln15;
            const int row = rowB + mi * 16 + lg * 4;
            float bvv;
            if (EPI == 2) bvv = (col < 1024) ? bias0[col] : bias1[col - 1024];
            else bvv = bias0[col];
#pragma unroll
            for (int r = 0; r < 4; ++r) {
                const float v = acc[mi][ni][r] + bvv;
                if (EPI == 0) {
                    C0[(size_t)(row + r) * N + col] = f2b(v);
                } else if (EPI == 1) {
                    Cf[(size_t)(row + r) * N + col] = v + X[(size_t)(row + r) * N + col];
                } else if (EPI == 2) {
                    if (col < 1024) C0[(size_t)(row + r) * 1024 + col] = f2b(v);
                    else C1[(size_t)(row + r) * 1024 + (col - 1024)] = f2b(v);
                } else {
                    Cf[(size_t)(row + r) * N + col] = v;
                }
            }
        }
    }
}

// ---------------------------------------------------------------------------
// MFMA cross-attention (HW-validated r9): one block per (b,h)
// ---------------------------------------------------------------------------
__global__ __launch_bounds__(256, 2) void k_attn_m(const unsigned short* __restrict__ Q,
                                                   const unsigned short* __restrict__ Kb,
                                                   const unsigned short* __restrict__ Vb,
                                                   unsigned short* __restrict__ Y) {
    __shared__ __align__(16) unsigned short sK[80 * 64];
    __shared__ __align__(16) unsigned short sV[64 * 96];
    __shared__ __align__(16) unsigned short sP[4][16 * 104];
    const int bh = blockIdx.x;
    const int b = bh >> 4, h = bh & 15;
    const int tid = threadIdx.x, wv = tid >> 6, ln = tid & 63;
    const int ln15 = ln & 15, lg = ln >> 4;

    for (int c = tid; c < 640; c += 256) {
        const int n = c >> 3, ci = c & 7;
        uint4 val = make_uint4(0u, 0u, 0u, 0u);
        if (n < 77) val = *(const uint4*)(Kb + (size_t)(b * 77 + n) * 1024 + h * 64 + ci * 8);
        *(uint4*)((char*)sK + n * 128 + ((ci * 16) ^ ((n & 7) << 4))) = val;
    }
    for (int i = tid; i < 64 * 96; i += 256) {
        const int d = i / 96, n = i - d * 96;
        unsigned short val = 0;
        if (n < 77) val = Vb[(size_t)(b * 77 + n) * 1024 + h * 64 + d];
        sV[i] = val;
    }
    for (int i = ln; i < 16 * 24; i += 64) {
        const int rr = i / 24, cc = i - rr * 24;
        sP[wv][rr * 104 + 80 + cc] = 0;
    }
    bf16x8 qf[4][2];
    const size_t qbase = (size_t)b * (243 * 1024) + h * 64;
#pragma unroll
    for (int mi = 0; mi < 4; ++mi) {
        int t = wv * 64 + mi * 16 + ln15;
        if (t > 242) t = 242;
#pragma unroll
        for (int ks = 0; ks < 2; ++ks)
            qf[mi][ks] = *(const bf16x8*)(Q + qbase + (size_t)t * 1024 + ks * 32 + lg * 8);
    }
    __syncthreads();

    const f32x4 fz = {0.f, 0.f, 0.f, 0.f};
    f32x4 yacc[4][4];
#pragma unroll
    for (int i = 0; i < 4; ++i)
#pragma unroll
        for (int j = 0; j < 4; ++j) yacc[i][j] = fz;

#pragma unroll
    for (int mi = 0; mi < 4; ++mi) {
        f32x4 sc[5];
#pragma unroll
        for (int ci = 0; ci < 5; ++ci) sc[ci] = fz;
#pragma unroll
        for (int ci = 0; ci < 5; ++ci) {
            const int n = ci * 16 + ln15;
#pragma unroll
            for (int ks = 0; ks < 2; ++ks) {
                const int kk = ks * 32 + lg * 8;
                bf16x8 kf = *(const bf16x8*)((const char*)sK + n * 128 + ((kk * 2) ^ ((n & 7) << 4)));
                sc[ci] = __builtin_amdgcn_mfma_f32_16x16x32_bf16(qf[mi][ks], kf, sc[ci], 0, 0, 0);
            }
        }
#pragma unroll
        for (int r = 0; r < 4; ++r) {
            float e[5];
            float mx = -1e30f;
#pragma unroll
            for (int ci = 0; ci < 5; ++ci) {
                const int n = ci * 16 + ln15;
                const float vv = (n < 77) ? sc[ci][r] * 0.125f : -1e30f;
                e[ci] = vv;
                mx = fmaxf(mx, vv);
            }
            mx = fmaxf(mx, __shfl_xor(mx, 1));
            mx = fmaxf(mx, __shfl_xor(mx, 2));
            mx = fmaxf(mx, __shfl_xor(mx, 4));
            mx = fmaxf(mx, __shfl_xor(mx, 8));
            float ssum = 0.f;
#pragma unroll
            for (int ci = 0; ci < 5; ++ci) {
                const int n = ci * 16 + ln15;
                const float ev = (n < 77) ? __expf(e[ci] - mx) : 0.f;
                e[ci] = ev;
                ssum += ev;
            }
            ssum += __shfl_xor(ssum, 1);
            ssum += __shfl_xor(ssum, 2);
            ssum += __shfl_xor(ssum, 4);
            ssum += __shfl_xor(ssum, 8);
            const float inv = 1.f / ssum;
            const int prow = lg * 4 + r;
#pragma unroll
            for (int ci = 0; ci < 5; ++ci)
                sP[wv][prow * 104 + ci * 16 + ln15] = f2b(e[ci] * inv);
        }
        __syncthreads();
#pragma unroll
        for (int ks = 0; ks < 3; ++ks) {
            bf16x8 pa = *(const bf16x8*)(sP[wv] + ln15 * 104 + ks * 32 + lg * 8);
#pragma unroll
            for (int di = 0; di < 4; ++di) {
                bf16x8 vf = *(const bf16x8*)(sV + (di * 16 + ln15) * 96 + ks * 32 + lg * 8);
                yacc[mi][di] = __builtin_amdgcn_mfma_f32_16x16x32_bf16(pa, vf, yacc[mi][di], 0, 0, 0);
            }
        }
        __syncthreads();
    }
    const size_t ybase = (size_t)b * (243 * 1024) + h * 64;
#pragma unroll
    for (int mi = 0; mi < 4; ++mi)
#pragma unroll
        for (int di = 0; di < 4; ++di)
#pragma unroll
            for (int r = 0; r < 4; ++r) {
                const int t = wv * 64 + mi * 16 + lg * 4 + r;
                if (t < 243) Y[ybase + (size_t)t * 1024 + di * 16 + ln15] = f2b(yacc[mi][di][r]);
            }
}

// ---------------------------------------------------------------------------
// Stylization (HW-validated)
// ---------------------------------------------------------------------------
__global__ __launch_bounds__(256) void k_act(const unsigned short* __restrict__ y,
                                             const float* __restrict__ eo,
                                             const float* __restrict__ g,
                                             const float* __restrict__ b,
                                             unsigned short* __restrict__ out) {
    const int row = blockIdx.x * 4 + (threadIdx.x >> 6);
    const int ln = threadIdx.x & 63;
    const int bb = row / 243;
    float v[16];
    const size_t base = (size_t)row * 1024 + ln * 16;
#pragma unroll
    for (int c = 0; c < 16; ++c) v[c] = b2f(y[base + c]);
    float s = 0.f, s2 = 0.f;
#pragma unroll
    for (int c = 0; c < 16; ++c) { s += v[c]; s2 += v[c] * v[c]; }
    for (int o = 1; o < 64; o <<= 1) { s += __shfl_xor(s, o); s2 += __shfl_xor(s2, o); }
    const float mean = s / 1024.f;
    const float rstd = rsqrtf(s2 / 1024.f - mean * mean + 1e-5f);
#pragma unroll
    for (int c = 0; c < 16; ++c) {
        const int kk = ln * 16 + c;
        const float nl = (v[c] - mean) * rstd * g[kk] + b[kk];
        const float hh = nl * (1.f + eo[(size_t)bb * 2048 + kk]) + eo[(size_t)bb * 2048 + 1024 + kk];
        out[base + c] = f2b(hh / (1.f + __expf(-hh)));
    }
}

// ---------------------------------------------------------------------------
extern "C" void kernel_launch(void* const* d_in, const int* in_sizes, int n_in,
                              void* d_out, int out_size, void* d_ws, size_t ws_size,
                              hipStream_t stream) {
    (void)in_sizes; (void)n_in; (void)out_size; (void)ws_size;

    const float* x     = (const float*)d_in[0];
    const float* xf    = (const float*)d_in[1];
    const float* emb   = (const float*)d_in[2];
    const float* ln_g  = (const float*)d_in[3];
    const float* ln_b  = (const float*)d_in[4];
    const float* tln_g = (const float*)d_in[5];
    const float* tln_b = (const float*)d_in[6];
    const float* Wq    = (const float*)d_in[7];
    const float* bq    = (const float*)d_in[8];
    const float* Wk    = (const float*)d_in[9];
    const float* bk    = (const float*)d_in[10];
    const float* Wv    = (const float*)d_in[11];
    const float* bv    = (const float*)d_in[12];
    const float* We    = (const float*)d_in[13];
    const float* be    = (const float*)d_in[14];
    const float* ln2_g = (const float*)d_in[15];
    const float* ln2_b = (const float*)d_in[16];
    const float* Wo    = (const float*)d_in[17];
    const float* bo    = (const float*)d_in[18];
    float* outp = (float*)d_out;

    char* ws = (char*)d_ws;
    constexpr size_t o_wq   = 0;
    constexpr size_t o_wkv  = o_wq + 2097152;
    constexpr size_t o_we   = o_wkv + 2097152;
    constexpr size_t o_wo   = o_we + 4194304;
    constexpr size_t o_se   = o_wo + 2097152;
    constexpr size_t o_eo   = o_se + 262144;
    constexpr size_t o_xn   = o_eo + 1048576;
    constexpr size_t o_qb   = o_xn + 63700992;
    constexpr size_t o_xfn  = o_qb + 63700992;
    constexpr size_t o_kb   = o_xfn + 10092544;
    constexpr size_t o_vb   = o_kb + 20185088;

    unsigned short* wqt  = (unsigned short*)(ws + o_wq);
    unsigned short* wkvt = (unsigned short*)(ws + o_wkv);
    unsigned short* wet  = (unsigned short*)(ws + o_we);
    unsigned short* wot  = (unsigned short*)(ws + o_wo);
    unsigned short* se   = (unsigned short*)(ws + o_se);
    float*          eo   = (float*)(ws + o_eo);
    unsigned short* xn   = (unsigned short*)(ws + o_xn);
    unsigned short* yb   = xn;                      // alias: xn dead after Q-GEMM
    unsigned short* qb   = (unsigned short*)(ws + o_qb);
    unsigned short* actb = qb;                      // alias: q dead after attention
    unsigned short* xfn  = (unsigned short*)(ws + o_xfn);
    unsigned short* kb   = (unsigned short*)(ws + o_kb);
    unsigned short* vb   = (unsigned short*)(ws + o_vb);

    // pre-passes
    k_ln<1024><<<7776, 256, 0, stream>>>(x, ln_g, ln_b, xn);
    k_ln<512><<<2464, 256, 0, stream>>>(xf, tln_g, tln_b, xfn);
    k_silu<<<512, 256, 0, stream>>>(emb, se);
    k_cvt<<<dim3(32, 32), 256, 0, stream>>>(Wq, wqt, 1024, 1024);
    k_cvt<<<dim3(32, 16), 256, 0, stream>>>(Wk, wkvt, 512, 1024);
    k_cvt<<<dim3(32, 16), 256, 0, stream>>>(Wv, wkvt + 1024 * 512, 512, 1024);
    k_cvt<<<dim3(64, 32), 256, 0, stream>>>(We, wet, 1024, 2048);
    k_cvt<<<dim3(32, 32), 256, 0, stream>>>(Wo, wot, 1024, 1024);

    // eo = silu(emb0) @ We + be  (f32 out)
    k_mm<3><<<dim3(1, 16), 256, 0, stream>>>(se, wet, be, nullptr,
                                             nullptr, nullptr, eo, nullptr, 2048, 1024);

    // projections
    k_mm<0><<<dim3(243, 8), 256, 0, stream>>>(xn, wqt, bq, nullptr,
                                              qb, nullptr, nullptr, nullptr, 1024, 1024);
    k_mm<2><<<dim3(77, 16), 256, 0, stream>>>(xfn, wkvt, bk, bv,
                                              kb, vb, nullptr, nullptr, 2048, 512);

    // attention
    k_attn_m<<<2048, 256, 0, stream>>>(qb, kb, vb, yb);

    // stylization
    k_act<<<7776, 256, 0, stream>>>(yb, eo, ln2_g, ln2_b, actb);

    // output projection + residual -> d_out (f32)
    k_mm<1><<<dim3(243, 8), 256, 0, stream>>>(actb, wot, bo, nullptr,
                                              nullptr, nullptr, outp, x, 1024, 1024);
}

// Round 12
// 397.278 us; speedup vs baseline: 55.7579x; 1.1307x over previous
//
#include <hip/hip_runtime.h>
#include <cstdint>

typedef __attribute__((ext_vector_type(8))) __bf16 bf16x8;
typedef __attribute__((ext_vector_type(4))) float f32x4;

__device__ __forceinline__ float b2f(unsigned short u) {
    union { uint32_t i; float f; } w; w.i = ((uint32_t)u) << 16; return w.f;
}
__device__ __forceinline__ unsigned short f2b(float f) {
    union { uint32_t i; float f; } w; w.f = f;
    uint32_t r = (w.i + 0x7FFFu + ((w.i >> 16) & 1u)) >> 16;
    return (unsigned short)r;
}

// 16B global -> LDS direct (wave-uniform LDS base; HW adds lane*16).
__device__ __forceinline__ void gl16(const unsigned short* g, unsigned short* l) {
    __builtin_amdgcn_global_load_lds(
        (const __attribute__((address_space(1))) void*)g,
        (__attribute__((address_space(3))) void*)l,
        16, 0, 0);
}

// ---------------------------------------------------------------------------
// Weight convert+transpose: W f32 (R x C) -> Wt bf16 (C x R)
// ---------------------------------------------------------------------------
__global__ __launch_bounds__(256) void k_cvt(const float* __restrict__ in,
                                             unsigned short* __restrict__ out,
                                             int R, int C) {
    __shared__ float s[32][33];
    const int c0 = blockIdx.x * 32, r0 = blockIdx.y * 32;
    const int tx = threadIdx.x & 31, ty = threadIdx.x >> 5;
#pragma unroll
    for (int i = 0; i < 4; ++i)
        s[ty + i * 8][tx] = in[(size_t)(r0 + ty + i * 8) * C + c0 + tx];
    __syncthreads();
#pragma unroll
    for (int i = 0; i < 4; ++i)
        out[(size_t)(c0 + ty + i * 8) * R + r0 + tx] = f2b(s[tx][ty + i * 8]);
}

// ---------------------------------------------------------------------------
// LayerNorm f32 -> bf16, one wave per row
// ---------------------------------------------------------------------------
template <int DIM>
__global__ __launch_bounds__(256) void k_ln(const float* __restrict__ in,
                                            const float* __restrict__ g,
                                            const float* __restrict__ b,
                                            unsigned short* __restrict__ out) {
    const int row = blockIdx.x * 4 + (threadIdx.x >> 6);
    const int ln = threadIdx.x & 63;
    constexpr int PL = DIM / 64;
    float v[PL];
    const size_t base = (size_t)row * DIM + (size_t)ln * PL;
#pragma unroll
    for (int c = 0; c < PL; ++c) v[c] = in[base + c];
    float s = 0.f, s2 = 0.f;
#pragma unroll
    for (int c = 0; c < PL; ++c) { s += v[c]; s2 += v[c] * v[c]; }
    for (int o = 1; o < 64; o <<= 1) { s += __shfl_xor(s, o); s2 += __shfl_xor(s2, o); }
    const float mean = s / DIM;
    const float rstd = rsqrtf(s2 / DIM - mean * mean + 1e-5f);
#pragma unroll
    for (int c = 0; c < PL; ++c) {
        const int kk = ln * PL + c;
        out[(size_t)row * DIM + kk] = f2b((v[c] - mean) * rstd * g[kk] + b[kk]);
    }
}

__global__ __launch_bounds__(256) void k_silu(const float* __restrict__ emb,
                                              unsigned short* __restrict__ se) {
    const int i = blockIdx.x * 256 + threadIdx.x;
    const int b = i >> 10, k = i & 1023;
    const float f = emb[(size_t)b * (243 * 1024) + k];
    se[i] = f2b(f / (1.f + __expf(-f)));
}

// ---------------------------------------------------------------------------
// MFMA GEMM, m97-structure + bijective XCD-chunked n-inner block swizzle (T1).
// Flat grid of (M/128)*(N/128) blocks; each XCD gets a contiguous m-chunk and
// sweeps n-panels inner -> A panel reused from L2 by 8 co-XCD blocks, B panels
// L2-resident per XCD.
// EPI 0: C0 bf16 | EPI 1: Cf f32 = acc+bias+X | EPI 2: KV split | EPI 3: Cf f32
// ---------------------------------------------------------------------------
template <int EPI>
__global__ __launch_bounds__(256, 2) void k_mm(
    const unsigned short* __restrict__ A, const unsigned short* __restrict__ Bt,
    const float* __restrict__ bias0, const float* __restrict__ bias1,
    unsigned short* __restrict__ C0, unsigned short* __restrict__ C1,
    float* __restrict__ Cf, const float* __restrict__ X,
    int N, int K) {
    __shared__ __align__(16) unsigned short sA[128 * 64];
    __shared__ __align__(16) unsigned short sB[128 * 64];
    const int tid = threadIdx.x, wv = tid >> 6, ln = tid & 63;
    const int wm = wv >> 1, wn = wv & 1;
    const int ln15 = ln & 15, lg = ln >> 4;

    // bijective XCD-chunk remap (m204), n-inner within chunk
    const int NN = N >> 7;
    const int nwg = gridDim.x;
    const int wg = blockIdx.x;
    const int q = nwg >> 3, r = nwg & 7;
    const int xcd = wg & 7, idx = wg >> 3;
    const int u = (xcd < r) ? (xcd * (q + 1) + idx)
                            : (r * (q + 1) + (xcd - r) * q + idx);
    const int m0 = (u / NN) * 128, n0 = (u % NN) * 128;

    const f32x4 fz = {0.f, 0.f, 0.f, 0.f};
    f32x4 acc[4][4];
#pragma unroll
    for (int i = 0; i < 4; ++i)
#pragma unroll
        for (int j = 0; j < 4; ++j) acc[i][j] = fz;

    const int lrow = ln >> 3;                  // 0..7: row within 8-row chunk
    const int sslot = (ln & 7) ^ lrow;         // pre-swizzled global 16B slot
    const unsigned short* ga = A + (size_t)(m0 + wv * 32 + lrow) * K + sslot * 8;
    const unsigned short* gb = Bt + (size_t)(n0 + wv * 32 + lrow) * K + sslot * 8;
    unsigned short* const lA = sA + (wv * 32) * 64;   // wave-uniform LDS bases
    unsigned short* const lB = sB + (wv * 32) * 64;

    for (int k0 = 0; k0 < K; k0 += 64) {
#pragma unroll
        for (int i = 0; i < 4; ++i) {
            gl16(ga + k0 + (size_t)i * 8 * K, lA + i * 8 * 64);
            gl16(gb + k0 + (size_t)i * 8 * K, lB + i * 8 * 64);
        }
        __syncthreads();   // vmcnt drained before barrier -> tile resident
        bf16x8 af[4][2], bf[4][2];
#pragma unroll
        for (int i = 0; i < 4; ++i) {
            const int ra2 = wm * 64 + i * 16 + ln15;
            const int rb2 = wn * 64 + i * 16 + ln15;
#pragma unroll
            for (int ks = 0; ks < 2; ++ks) {
                const int slot = ks * 4 + lg;
                af[i][ks] = *(const bf16x8*)(sA + ra2 * 64 + ((slot ^ (ra2 & 7)) * 8));
                bf[i][ks] = *(const bf16x8*)(sB + rb2 * 64 + ((slot ^ (rb2 & 7)) * 8));
            }
        }
#pragma unroll
        for (int mi = 0; mi < 4; ++mi)
#pragma unroll
            for (int ni = 0; ni < 4; ++ni) {
                acc[mi][ni] = __builtin_amdgcn_mfma_f32_16x16x32_bf16(af[mi][0], bf[ni][0], acc[mi][ni], 0, 0, 0);
                acc[mi][ni] = __builtin_amdgcn_mfma_f32_16x16x32_bf16(af[mi][1], bf[ni][1], acc[mi][ni], 0, 0, 0);
            }
        __syncthreads();   // protect LDS from next stage
    }

    const int colB = n0 + wn * 64;
    const int rowB = m0 + wm * 64;
#pragma unroll
    for (int mi = 0; mi < 4; ++mi) {
#pragma unroll
        for (int ni = 0; ni < 4; ++ni) {
            const int col = colB + ni * 16 + ln15;
            const int row = rowB + mi * 16 + lg * 4;
            float bvv;
            if (EPI == 2) bvv = (col < 1024) ? bias0[col] : bias1[col - 1024];
            else bvv = bias0[col];
#pragma unroll
            for (int r2 = 0; r2 < 4; ++r2) {
                const float v = acc[mi][ni][r2] + bvv;
                if (EPI == 0) {
                    C0[(size_t)(row + r2) * N + col] = f2b(v);
                } else if (EPI == 1) {
                    Cf[(size_t)(row + r2) * N + col] = v + X[(size_t)(row + r2) * N + col];
                } else if (EPI == 2) {
                    if (col < 1024) C0[(size_t)(row + r2) * 1024 + col] = f2b(v);
                    else C1[(size_t)(row + r2) * 1024 + (col - 1024)] = f2b(v);
                } else {
                    Cf[(size_t)(row + r2) * N + col] = v;
                }
            }
        }
    }
}

// ---------------------------------------------------------------------------
// MFMA cross-attention (HW-validated r9): one block per (b,h)
// ---------------------------------------------------------------------------
__global__ __launch_bounds__(256, 2) void k_attn_m(const unsigned short* __restrict__ Q,
                                                   const unsigned short* __restrict__ Kb,
                                                   const unsigned short* __restrict__ Vb,
                                                   unsigned short* __restrict__ Y) {
    __shared__ __align__(16) unsigned short sK[80 * 64];
    __shared__ __align__(16) unsigned short sV[64 * 96];
    __shared__ __align__(16) unsigned short sP[4][16 * 104];
    const int bh = blockIdx.x;
    const int b = bh >> 4, h = bh & 15;
    const int tid = threadIdx.x, wv = tid >> 6, ln = tid & 63;
    const int ln15 = ln & 15, lg = ln >> 4;

    for (int c = tid; c < 640; c += 256) {
        const int n = c >> 3, ci = c & 7;
        uint4 val = make_uint4(0u, 0u, 0u, 0u);
        if (n < 77) val = *(const uint4*)(Kb + (size_t)(b * 77 + n) * 1024 + h * 64 + ci * 8);
        *(uint4*)((char*)sK + n * 128 + ((ci * 16) ^ ((n & 7) << 4))) = val;
    }
    for (int i = tid; i < 64 * 96; i += 256) {
        const int d = i / 96, n = i - d * 96;
        unsigned short val = 0;
        if (n < 77) val = Vb[(size_t)(b * 77 + n) * 1024 + h * 64 + d];
        sV[i] = val;
    }
    for (int i = ln; i < 16 * 24; i += 64) {
        const int rr = i / 24, cc = i - rr * 24;
        sP[wv][rr * 104 + 80 + cc] = 0;
    }
    bf16x8 qf[4][2];
    const size_t qbase = (size_t)b * (243 * 1024) + h * 64;
#pragma unroll
    for (int mi = 0; mi < 4; ++mi) {
        int t = wv * 64 + mi * 16 + ln15;
        if (t > 242) t = 242;
#pragma unroll
        for (int ks = 0; ks < 2; ++ks)
            qf[mi][ks] = *(const bf16x8*)(Q + qbase + (size_t)t * 1024 + ks * 32 + lg * 8);
    }
    __syncthreads();

    const f32x4 fz = {0.f, 0.f, 0.f, 0.f};
    f32x4 yacc[4][4];
#pragma unroll
    for (int i = 0; i < 4; ++i)
#pragma unroll
        for (int j = 0; j < 4; ++j) yacc[i][j] = fz;

#pragma unroll
    for (int mi = 0; mi < 4; ++mi) {
        f32x4 sc[5];
#pragma unroll
        for (int ci = 0; ci < 5; ++ci) sc[ci] = fz;
#pragma unroll
        for (int ci = 0; ci < 5; ++ci) {
            const int n = ci * 16 + ln15;
#pragma unroll
            for (int ks = 0; ks < 2; ++ks) {
                const int kk = ks * 32 + lg * 8;
                bf16x8 kf = *(const bf16x8*)((const char*)sK + n * 128 + ((kk * 2) ^ ((n & 7) << 4)));
                sc[ci] = __builtin_amdgcn_mfma_f32_16x16x32_bf16(qf[mi][ks], kf, sc[ci], 0, 0, 0);
            }
        }
#pragma unroll
        for (int r = 0; r < 4; ++r) {
            float e[5];
            float mx = -1e30f;
#pragma unroll
            for (int ci = 0; ci < 5; ++ci) {
                const int n = ci * 16 + ln15;
                const float vv = (n < 77) ? sc[ci][r] * 0.125f : -1e30f;
                e[ci] = vv;
                mx = fmaxf(mx, vv);
            }
            mx = fmaxf(mx, __shfl_xor(mx, 1));
            mx = fmaxf(mx, __shfl_xor(mx, 2));
            mx = fmaxf(mx, __shfl_xor(mx, 4));
            mx = fmaxf(mx, __shfl_xor(mx, 8));
            float ssum = 0.f;
#pragma unroll
            for (int ci = 0; ci < 5; ++ci) {
                const int n = ci * 16 + ln15;
                const float ev = (n < 77) ? __expf(e[ci] - mx) : 0.f;
                e[ci] = ev;
                ssum += ev;
            }
            ssum += __shfl_xor(ssum, 1);
            ssum += __shfl_xor(ssum, 2);
            ssum += __shfl_xor(ssum, 4);
            ssum += __shfl_xor(ssum, 8);
            const float inv = 1.f / ssum;
            const int prow = lg * 4 + r;
#pragma unroll
            for (int ci = 0; ci < 5; ++ci)
                sP[wv][prow * 104 + ci * 16 + ln15] = f2b(e[ci] * inv);
        }
        __syncthreads();
#pragma unroll
        for (int ks = 0; ks < 3; ++ks) {
            bf16x8 pa = *(const bf16x8*)(sP[wv] + ln15 * 104 + ks * 32 + lg * 8);
#pragma unroll
            for (int di = 0; di < 4; ++di) {
                bf16x8 vf = *(const bf16x8*)(sV + (di * 16 + ln15) * 96 + ks * 32 + lg * 8);
                yacc[mi][di] = __builtin_amdgcn_mfma_f32_16x16x32_bf16(pa, vf, yacc[mi][di], 0, 0, 0);
            }
        }
        __syncthreads();
    }
    const size_t ybase = (size_t)b * (243 * 1024) + h * 64;
#pragma unroll
    for (int mi = 0; mi < 4; ++mi)
#pragma unroll
        for (int di = 0; di < 4; ++di)
#pragma unroll
            for (int r = 0; r < 4; ++r) {
                const int t = wv * 64 + mi * 16 + lg * 4 + r;
                if (t < 243) Y[ybase + (size_t)t * 1024 + di * 16 + ln15] = f2b(yacc[mi][di][r]);
            }
}

// ---------------------------------------------------------------------------
// Stylization (HW-validated)
// ---------------------------------------------------------------------------
__global__ __launch_bounds__(256) void k_act(const unsigned short* __restrict__ y,
                                             const float* __restrict__ eo,
                                             const float* __restrict__ g,
                                             const float* __restrict__ b,
                                             unsigned short* __restrict__ out) {
    const int row = blockIdx.x * 4 + (threadIdx.x >> 6);
    const int ln = threadIdx.x & 63;
    const int bb = row / 243;
    float v[16];
    const size_t base = (size_t)row * 1024 + ln * 16;
#pragma unroll
    for (int c = 0; c < 16; ++c) v[c] = b2f(y[base + c]);
    float s = 0.f, s2 = 0.f;
#pragma unroll
    for (int c = 0; c < 16; ++c) { s += v[c]; s2 += v[c] * v[c]; }
    for (int o = 1; o < 64; o <<= 1) { s += __shfl_xor(s, o); s2 += __shfl_xor(s2, o); }
    const float mean = s / 1024.f;
    const float rstd = rsqrtf(s2 / 1024.f - mean * mean + 1e-5f);
#pragma unroll
    for (int c = 0; c < 16; ++c) {
        const int kk = ln * 16 + c;
        const float nl = (v[c] - mean) * rstd * g[kk] + b[kk];
        const float hh = nl * (1.f + eo[(size_t)bb * 2048 + kk]) + eo[(size_t)bb * 2048 + 1024 + kk];
        out[base + c] = f2b(hh / (1.f + __expf(-hh)));
    }
}

// ---------------------------------------------------------------------------
extern "C" void kernel_launch(void* const* d_in, const int* in_sizes, int n_in,
                              void* d_out, int out_size, void* d_ws, size_t ws_size,
                              hipStream_t stream) {
    (void)in_sizes; (void)n_in; (void)out_size; (void)ws_size;

    const float* x     = (const float*)d_in[0];
    const float* xf    = (const float*)d_in[1];
    const float* emb   = (const float*)d_in[2];
    const float* ln_g  = (const float*)d_in[3];
    const float* ln_b  = (const float*)d_in[4];
    const float* tln_g = (const float*)d_in[5];
    const float* tln_b = (const float*)d_in[6];
    const float* Wq    = (const float*)d_in[7];
    const float* bq    = (const float*)d_in[8];
    const float* Wk    = (const float*)d_in[9];
    const float* bk    = (const float*)d_in[10];
    const float* Wv    = (const float*)d_in[11];
    const float* bv    = (const float*)d_in[12];
    const float* We    = (const float*)d_in[13];
    const float* be    = (const float*)d_in[14];
    const float* ln2_g = (const float*)d_in[15];
    const float* ln2_b = (const float*)d_in[16];
    const float* Wo    = (const float*)d_in[17];
    const float* bo    = (const float*)d_in[18];
    float* outp = (float*)d_out;

    char* ws = (char*)d_ws;
    constexpr size_t o_wq   = 0;
    constexpr size_t o_wkv  = o_wq + 2097152;
    constexpr size_t o_we   = o_wkv + 2097152;
    constexpr size_t o_wo   = o_we + 4194304;
    constexpr size_t o_se   = o_wo + 2097152;
    constexpr size_t o_eo   = o_se + 262144;
    constexpr size_t o_xn   = o_eo + 1048576;
    constexpr size_t o_qb   = o_xn + 63700992;
    constexpr size_t o_xfn  = o_qb + 63700992;
    constexpr size_t o_kb   = o_xfn + 10092544;
    constexpr size_t o_vb   = o_kb + 20185088;

    unsigned short* wqt  = (unsigned short*)(ws + o_wq);
    unsigned short* wkvt = (unsigned short*)(ws + o_wkv);
    unsigned short* wet  = (unsigned short*)(ws + o_we);
    unsigned short* wot  = (unsigned short*)(ws + o_wo);
    unsigned short* se   = (unsigned short*)(ws + o_se);
    float*          eo   = (float*)(ws + o_eo);
    unsigned short* xn   = (unsigned short*)(ws + o_xn);
    unsigned short* yb   = xn;                      // alias: xn dead after Q-GEMM
    unsigned short* qb   = (unsigned short*)(ws + o_qb);
    unsigned short* actb = qb;                      // alias: q dead after attention
    unsigned short* xfn  = (unsigned short*)(ws + o_xfn);
    unsigned short* kb   = (unsigned short*)(ws + o_kb);
    unsigned short* vb   = (unsigned short*)(ws + o_vb);

    // pre-passes
    k_ln<1024><<<7776, 256, 0, stream>>>(x, ln_g, ln_b, xn);
    k_ln<512><<<2464, 256, 0, stream>>>(xf, tln_g, tln_b, xfn);
    k_silu<<<512, 256, 0, stream>>>(emb, se);
    k_cvt<<<dim3(32, 32), 256, 0, stream>>>(Wq, wqt, 1024, 1024);
    k_cvt<<<dim3(32, 16), 256, 0, stream>>>(Wk, wkvt, 512, 1024);
    k_cvt<<<dim3(32, 16), 256, 0, stream>>>(Wv, wkvt + 1024 * 512, 512, 1024);
    k_cvt<<<dim3(64, 32), 256, 0, stream>>>(We, wet, 1024, 2048);
    k_cvt<<<dim3(32, 32), 256, 0, stream>>>(Wo, wot, 1024, 1024);

    // eo = silu(emb0) @ We + be  (f32 out); flat grid 1*16
    k_mm<3><<<16, 256, 0, stream>>>(se, wet, be, nullptr,
                                    nullptr, nullptr, eo, nullptr, 2048, 1024);

    // projections (flat grids, XCD-chunked swizzle in-kernel)
    k_mm<0><<<243 * 8, 256, 0, stream>>>(xn, wqt, bq, nullptr,
                                         qb, nullptr, nullptr, nullptr, 1024, 1024);
    k_mm<2><<<77 * 16, 256, 0, stream>>>(xfn, wkvt, bk, bv,
                                         kb, vb, nullptr, nullptr, 2048, 512);

    // attention
    k_attn_m<<<2048, 256, 0, stream>>>(qb, kb, vb, yb);

    // stylization
    k_act<<<7776, 256, 0, stream>>>(yb, eo, ln2_g, ln2_b, actb);

    // output projection + residual -> d_out (f32)
    k_mm<1><<<243 * 8, 256, 0, stream>>>(actb, wot, bo, nullptr,
                                         nullptr, nullptr, outp, x, 1024, 1024);
}

// Round 13
// 392.624 us; speedup vs baseline: 56.4187x; 1.0119x over previous
//
#include <hip/hip_runtime.h>
#include <cstdint>

typedef __attribute__((ext_vector_type(8))) __bf16 bf16x8;
typedef __attribute__((ext_vector_type(4))) float f32x4;
typedef __attribute__((ext_vector_type(8))) unsigned short ushort8v;

__device__ __forceinline__ float b2f(unsigned short u) {
    union { uint32_t i; float f; } w; w.i = ((uint32_t)u) << 16; return w.f;
}
__device__ __forceinline__ unsigned short f2b(float f) {
    union { uint32_t i; float f; } w; w.f = f;
    uint32_t r = (w.i + 0x7FFFu + ((w.i >> 16) & 1u)) >> 16;
    return (unsigned short)r;
}

// 16B global -> LDS direct (wave-uniform LDS base; HW adds lane*16).
__device__ __forceinline__ void gl16(const unsigned short* g, unsigned short* l) {
    __builtin_amdgcn_global_load_lds(
        (const __attribute__((address_space(1))) void*)g,
        (__attribute__((address_space(3))) void*)l,
        16, 0, 0);
}

// ---------------------------------------------------------------------------
// All weight convert+transposes in ONE kernel: block-range dispatch.
// Same 32x32 tile algorithm as the validated k_cvt.
// ---------------------------------------------------------------------------
__global__ __launch_bounds__(256) void k_cvt_all(
    const float* __restrict__ Wq, const float* __restrict__ Wk,
    const float* __restrict__ Wv, const float* __restrict__ We,
    const float* __restrict__ Wo,
    unsigned short* __restrict__ wqt, unsigned short* __restrict__ wkvt,
    unsigned short* __restrict__ wet, unsigned short* __restrict__ wot) {
    __shared__ float s[32][33];
    int bid = blockIdx.x;
    const float* in; unsigned short* out; int R, C;
    if (bid < 1024)      { in = Wq; out = wqt;              R = 1024; C = 1024; }
    else if (bid < 1536) { bid -= 1024; in = Wk; out = wkvt;             R = 512;  C = 1024; }
    else if (bid < 2048) { bid -= 1536; in = Wv; out = wkvt + 1024 * 512; R = 512;  C = 1024; }
    else if (bid < 4096) { bid -= 2048; in = We; out = wet;              R = 1024; C = 2048; }
    else                 { bid -= 4096; in = Wo; out = wot;              R = 1024; C = 1024; }
    const int ctiles = C >> 5;
    const int c0 = (bid % ctiles) * 32, r0 = (bid / ctiles) * 32;
    const int tx = threadIdx.x & 31, ty = threadIdx.x >> 5;
#pragma unroll
    for (int i = 0; i < 4; ++i)
        s[ty + i * 8][tx] = in[(size_t)(r0 + ty + i * 8) * C + c0 + tx];
    __syncthreads();
#pragma unroll
    for (int i = 0; i < 4; ++i)
        out[(size_t)(c0 + ty + i * 8) * R + r0 + tx] = f2b(s[tx][ty + i * 8]);
}

// ---------------------------------------------------------------------------
// LayerNorm f32 -> bf16, one wave per row (vectorized loads/stores)
// ---------------------------------------------------------------------------
template <int DIM>
__global__ __launch_bounds__(256) void k_ln(const float* __restrict__ in,
                                            const float* __restrict__ g,
                                            const float* __restrict__ b,
                                            unsigned short* __restrict__ out) {
    const int row = blockIdx.x * 4 + (threadIdx.x >> 6);
    const int ln = threadIdx.x & 63;
    constexpr int PL = DIM / 64;
    float v[PL];
    const size_t base = (size_t)row * DIM + (size_t)ln * PL;
    const float4* p4 = (const float4*)(in + base);
#pragma unroll
    for (int c = 0; c < PL / 4; ++c) {
        const float4 t = p4[c];
        v[c * 4 + 0] = t.x; v[c * 4 + 1] = t.y; v[c * 4 + 2] = t.z; v[c * 4 + 3] = t.w;
    }
    float s = 0.f, s2 = 0.f;
#pragma unroll
    for (int c = 0; c < PL; ++c) { s += v[c]; s2 += v[c] * v[c]; }
    for (int o = 1; o < 64; o <<= 1) { s += __shfl_xor(s, o); s2 += __shfl_xor(s2, o); }
    const float mean = s / DIM;
    const float rstd = rsqrtf(s2 / DIM - mean * mean + 1e-5f);
    const float4* g4 = (const float4*)(g + ln * PL);
    const float4* b4 = (const float4*)(b + ln * PL);
#pragma unroll
    for (int c0 = 0; c0 < PL; c0 += 8) {
        ushort8v yv;
#pragma unroll
        for (int j = 0; j < 8; ++j) {
            const int c = c0 + j;
            const float gg = ((const float*)g4)[c];
            const float bb = ((const float*)b4)[c];
            yv[j] = f2b((v[c] - mean) * rstd * gg + bb);
        }
        *(ushort8v*)(out + base + c0) = yv;
    }
}

__global__ __launch_bounds__(256) void k_silu(const float* __restrict__ emb,
                                              unsigned short* __restrict__ se) {
    const int i = blockIdx.x * 256 + threadIdx.x;
    const int b = i >> 10, k = i & 1023;
    const float f = emb[(size_t)b * (243 * 1024) + k];
    se[i] = f2b(f / (1.f + __expf(-f)));
}

// ---------------------------------------------------------------------------
// MFMA GEMM (validated r11/r12): m97 staging + bijective XCD n-inner swizzle.
// EPI 0: C0 bf16 | EPI 1: Cf f32 = acc+bias+X | EPI 2: KV split | EPI 3: Cf f32
// ---------------------------------------------------------------------------
template <int EPI>
__global__ __launch_bounds__(256, 2) void k_mm(
    const unsigned short* __restrict__ A, const unsigned short* __restrict__ Bt,
    const float* __restrict__ bias0, const float* __restrict__ bias1,
    unsigned short* __restrict__ C0, unsigned short* __restrict__ C1,
    float* __restrict__ Cf, const float* __restrict__ X,
    int N, int K) {
    __shared__ __align__(16) unsigned short sA[128 * 64];
    __shared__ __align__(16) unsigned short sB[128 * 64];
    const int tid = threadIdx.x, wv = tid >> 6, ln = tid & 63;
    const int wm = wv >> 1, wn = wv & 1;
    const int ln15 = ln & 15, lg = ln >> 4;

    const int NN = N >> 7;
    const int nwg = gridDim.x;
    const int wg = blockIdx.x;
    const int q = nwg >> 3, r = nwg & 7;
    const int xcd = wg & 7, idx = wg >> 3;
    const int u = (xcd < r) ? (xcd * (q + 1) + idx)
                            : (r * (q + 1) + (xcd - r) * q + idx);
    const int m0 = (u / NN) * 128, n0 = (u % NN) * 128;

    const f32x4 fz = {0.f, 0.f, 0.f, 0.f};
    f32x4 acc[4][4];
#pragma unroll
    for (int i = 0; i < 4; ++i)
#pragma unroll
        for (int j = 0; j < 4; ++j) acc[i][j] = fz;

    const int lrow = ln >> 3;
    const int sslot = (ln & 7) ^ lrow;
    const unsigned short* ga = A + (size_t)(m0 + wv * 32 + lrow) * K + sslot * 8;
    const unsigned short* gb = Bt + (size_t)(n0 + wv * 32 + lrow) * K + sslot * 8;
    unsigned short* const lA = sA + (wv * 32) * 64;
    unsigned short* const lB = sB + (wv * 32) * 64;

    for (int k0 = 0; k0 < K; k0 += 64) {
#pragma unroll
        for (int i = 0; i < 4; ++i) {
            gl16(ga + k0 + (size_t)i * 8 * K, lA + i * 8 * 64);
            gl16(gb + k0 + (size_t)i * 8 * K, lB + i * 8 * 64);
        }
        __syncthreads();
        bf16x8 af[4][2], bf[4][2];
#pragma unroll
        for (int i = 0; i < 4; ++i) {
            const int ra2 = wm * 64 + i * 16 + ln15;
            const int rb2 = wn * 64 + i * 16 + ln15;
#pragma unroll
            for (int ks = 0; ks < 2; ++ks) {
                const int slot = ks * 4 + lg;
                af[i][ks] = *(const bf16x8*)(sA + ra2 * 64 + ((slot ^ (ra2 & 7)) * 8));
                bf[i][ks] = *(const bf16x8*)(sB + rb2 * 64 + ((slot ^ (rb2 & 7)) * 8));
            }
        }
#pragma unroll
        for (int mi = 0; mi < 4; ++mi)
#pragma unroll
            for (int ni = 0; ni < 4; ++ni) {
                acc[mi][ni] = __builtin_amdgcn_mfma_f32_16x16x32_bf16(af[mi][0], bf[ni][0], acc[mi][ni], 0, 0, 0);
                acc[mi][ni] = __builtin_amdgcn_mfma_f32_16x16x32_bf16(af[mi][1], bf[ni][1], acc[mi][ni], 0, 0, 0);
            }
        __syncthreads();
    }

    const int colB = n0 + wn * 64;
    const int rowB = m0 + wm * 64;
#pragma unroll
    for (int mi = 0; mi < 4; ++mi) {
#pragma unroll
        for (int ni = 0; ni < 4; ++ni) {
            const int col = colB + ni * 16 + ln15;
            const int row = rowB + mi * 16 + lg * 4;
            float bvv;
            if (EPI == 2) bvv = (col < 1024) ? bias0[col] : bias1[col - 1024];
            else bvv = bias0[col];
#pragma unroll
            for (int r2 = 0; r2 < 4; ++r2) {
                const float v = acc[mi][ni][r2] + bvv;
                if (EPI == 0) {
                    C0[(size_t)(row + r2) * N + col] = f2b(v);
                } else if (EPI == 1) {
                    Cf[(size_t)(row + r2) * N + col] = v + X[(size_t)(row + r2) * N + col];
                } else if (EPI == 2) {
                    if (col < 1024) C0[(size_t)(row + r2) * 1024 + col] = f2b(v);
                    else C1[(size_t)(row + r2) * 1024 + (col - 1024)] = f2b(v);
                } else {
                    Cf[(size_t)(row + r2) * N + col] = v;
                }
            }
        }
    }
}

// ---------------------------------------------------------------------------
// MFMA cross-attention: one block per (b,h).
// r13 change: removed per-mi __syncthreads() — sP is strictly per-wave
// (written+read only by its own wave, lockstep lanes), sK/sV read-only after
// the single staging barrier. Waves now run decoupled.
// ---------------------------------------------------------------------------
__global__ __launch_bounds__(256, 2) void k_attn_m(const unsigned short* __restrict__ Q,
                                                   const unsigned short* __restrict__ Kb,
                                                   const unsigned short* __restrict__ Vb,
                                                   unsigned short* __restrict__ Y) {
    __shared__ __align__(16) unsigned short sK[80 * 64];
    __shared__ __align__(16) unsigned short sV[64 * 96];
    __shared__ __align__(16) unsigned short sP[4][16 * 104];
    const int bh = blockIdx.x;
    const int b = bh >> 4, h = bh & 15;
    const int tid = threadIdx.x, wv = tid >> 6, ln = tid & 63;
    const int ln15 = ln & 15, lg = ln >> 4;

    for (int c = tid; c < 640; c += 256) {
        const int n = c >> 3, ci = c & 7;
        uint4 val = make_uint4(0u, 0u, 0u, 0u);
        if (n < 77) val = *(const uint4*)(Kb + (size_t)(b * 77 + n) * 1024 + h * 64 + ci * 8);
        *(uint4*)((char*)sK + n * 128 + ((ci * 16) ^ ((n & 7) << 4))) = val;
    }
    for (int i = tid; i < 64 * 96; i += 256) {
        const int d = i / 96, n = i - d * 96;
        unsigned short val = 0;
        if (n < 77) val = Vb[(size_t)(b * 77 + n) * 1024 + h * 64 + d];
        sV[i] = val;
    }
    for (int i = ln; i < 16 * 24; i += 64) {
        const int rr = i / 24, cc = i - rr * 24;
        sP[wv][rr * 104 + 80 + cc] = 0;
    }
    bf16x8 qf[4][2];
    const size_t qbase = (size_t)b * (243 * 1024) + h * 64;
#pragma unroll
    for (int mi = 0; mi < 4; ++mi) {
        int t = wv * 64 + mi * 16 + ln15;
        if (t > 242) t = 242;
#pragma unroll
        for (int ks = 0; ks < 2; ++ks)
            qf[mi][ks] = *(const bf16x8*)(Q + qbase + (size_t)t * 1024 + ks * 32 + lg * 8);
    }
    __syncthreads();   // sK/sV staged; the ONLY barrier in this kernel

    const f32x4 fz = {0.f, 0.f, 0.f, 0.f};
    f32x4 yacc[4][4];
#pragma unroll
    for (int i = 0; i < 4; ++i)
#pragma unroll
        for (int j = 0; j < 4; ++j) yacc[i][j] = fz;

#pragma unroll
    for (int mi = 0; mi < 4; ++mi) {
        f32x4 sc[5];
#pragma unroll
        for (int ci = 0; ci < 5; ++ci) sc[ci] = fz;
#pragma unroll
        for (int ci = 0; ci < 5; ++ci) {
            const int n = ci * 16 + ln15;
#pragma unroll
            for (int ks = 0; ks < 2; ++ks) {
                const int kk = ks * 32 + lg * 8;
                bf16x8 kf = *(const bf16x8*)((const char*)sK + n * 128 + ((kk * 2) ^ ((n & 7) << 4)));
                sc[ci] = __builtin_amdgcn_mfma_f32_16x16x32_bf16(qf[mi][ks], kf, sc[ci], 0, 0, 0);
            }
        }
#pragma unroll
        for (int r = 0; r < 4; ++r) {
            float e[5];
            float mx = -1e30f;
#pragma unroll
            for (int ci = 0; ci < 5; ++ci) {
                const int n = ci * 16 + ln15;
                const float vv = (n < 77) ? sc[ci][r] * 0.125f : -1e30f;
                e[ci] = vv;
                mx = fmaxf(mx, vv);
            }
            mx = fmaxf(mx, __shfl_xor(mx, 1));
            mx = fmaxf(mx, __shfl_xor(mx, 2));
            mx = fmaxf(mx, __shfl_xor(mx, 4));
            mx = fmaxf(mx, __shfl_xor(mx, 8));
            float ssum = 0.f;
#pragma unroll
            for (int ci = 0; ci < 5; ++ci) {
                const int n = ci * 16 + ln15;
                const float ev = (n < 77) ? __expf(e[ci] - mx) : 0.f;
                e[ci] = ev;
                ssum += ev;
            }
            ssum += __shfl_xor(ssum, 1);
            ssum += __shfl_xor(ssum, 2);
            ssum += __shfl_xor(ssum, 4);
            ssum += __shfl_xor(ssum, 8);
            const float inv = 1.f / ssum;
            const int prow = lg * 4 + r;
#pragma unroll
            for (int ci = 0; ci < 5; ++ci)
                sP[wv][prow * 104 + ci * 16 + ln15] = f2b(e[ci] * inv);
        }
        // no barrier: sP[wv] is wave-private; compiler orders via lgkmcnt
#pragma unroll
        for (int ks = 0; ks < 3; ++ks) {
            bf16x8 pa = *(const bf16x8*)(sP[wv] + ln15 * 104 + ks * 32 + lg * 8);
#pragma unroll
            for (int di = 0; di < 4; ++di) {
                bf16x8 vf = *(const bf16x8*)(sV + (di * 16 + ln15) * 96 + ks * 32 + lg * 8);
                yacc[mi][di] = __builtin_amdgcn_mfma_f32_16x16x32_bf16(pa, vf, yacc[mi][di], 0, 0, 0);
            }
        }
    }
    const size_t ybase = (size_t)b * (243 * 1024) + h * 64;
#pragma unroll
    for (int mi = 0; mi < 4; ++mi)
#pragma unroll
        for (int di = 0; di < 4; ++di)
#pragma unroll
            for (int r = 0; r < 4; ++r) {
                const int t = wv * 64 + mi * 16 + lg * 4 + r;
                if (t < 243) Y[ybase + (size_t)t * 1024 + di * 16 + ln15] = f2b(yacc[mi][di][r]);
            }
}

// ---------------------------------------------------------------------------
// Stylization (vectorized r13)
// ---------------------------------------------------------------------------
__global__ __launch_bounds__(256) void k_act(const unsigned short* __restrict__ y,
                                             const float* __restrict__ eo,
                                             const float* __restrict__ g,
                                             const float* __restrict__ b,
                                             unsigned short* __restrict__ out) {
    const int row = blockIdx.x * 4 + (threadIdx.x >> 6);
    const int ln = threadIdx.x & 63;
    const int bb = row / 243;
    float v[16];
    const size_t base = (size_t)row * 1024 + ln * 16;
#pragma unroll
    for (int c0 = 0; c0 < 16; c0 += 8) {
        const ushort8v t = *(const ushort8v*)(y + base + c0);
#pragma unroll
        for (int j = 0; j < 8; ++j) v[c0 + j] = b2f(t[j]);
    }
    float s = 0.f, s2 = 0.f;
#pragma unroll
    for (int c = 0; c < 16; ++c) { s += v[c]; s2 += v[c] * v[c]; }
    for (int o = 1; o < 64; o <<= 1) { s += __shfl_xor(s, o); s2 += __shfl_xor(s2, o); }
    const float mean = s / 1024.f;
    const float rstd = rsqrtf(s2 / 1024.f - mean * mean + 1e-5f);
    const float* gp = g + ln * 16;
    const float* bp = b + ln * 16;
    const float* sc = eo + (size_t)bb * 2048 + ln * 16;
    const float* sh = sc + 1024;
#pragma unroll
    for (int c0 = 0; c0 < 16; c0 += 8) {
        ushort8v yv;
#pragma unroll
        for (int j = 0; j < 8; ++j) {
            const int c = c0 + j;
            const float nl = (v[c] - mean) * rstd * gp[c] + bp[c];
            const float hh = nl * (1.f + sc[c]) + sh[c];
            yv[j] = f2b(hh / (1.f + __expf(-hh)));
        }
        *(ushort8v*)(out + base + c0) = yv;
    }
}

// ---------------------------------------------------------------------------
extern "C" void kernel_launch(void* const* d_in, const int* in_sizes, int n_in,
                              void* d_out, int out_size, void* d_ws, size_t ws_size,
                              hipStream_t stream) {
    (void)in_sizes; (void)n_in; (void)out_size; (void)ws_size;

    const float* x     = (const float*)d_in[0];
    const float* xf    = (const float*)d_in[1];
    const float* emb   = (const float*)d_in[2];
    const float* ln_g  = (const float*)d_in[3];
    const float* ln_b  = (const float*)d_in[4];
    const float* tln_g = (const float*)d_in[5];
    const float* tln_b = (const float*)d_in[6];
    const float* Wq    = (const float*)d_in[7];
    const float* bq    = (const float*)d_in[8];
    const float* Wk    = (const float*)d_in[9];
    const float* bk    = (const float*)d_in[10];
    const float* Wv    = (const float*)d_in[11];
    const float* bv    = (const float*)d_in[12];
    const float* We    = (const float*)d_in[13];
    const float* be    = (const float*)d_in[14];
    const float* ln2_g = (const float*)d_in[15];
    const float* ln2_b = (const float*)d_in[16];
    const float* Wo    = (const float*)d_in[17];
    const float* bo    = (const float*)d_in[18];
    float* outp = (float*)d_out;

    char* ws = (char*)d_ws;
    constexpr size_t o_wq   = 0;
    constexpr size_t o_wkv  = o_wq + 2097152;
    constexpr size_t o_we   = o_wkv + 2097152;
    constexpr size_t o_wo   = o_we + 4194304;
    constexpr size_t o_se   = o_wo + 2097152;
    constexpr size_t o_eo   = o_se + 262144;
    constexpr size_t o_xn   = o_eo + 1048576;
    constexpr size_t o_qb   = o_xn + 63700992;
    constexpr size_t o_xfn  = o_qb + 63700992;
    constexpr size_t o_kb   = o_xfn + 10092544;
    constexpr size_t o_vb   = o_kb + 20185088;

    unsigned short* wqt  = (unsigned short*)(ws + o_wq);
    unsigned short* wkvt = (unsigned short*)(ws + o_wkv);
    unsigned short* wet  = (unsigned short*)(ws + o_we);
    unsigned short* wot  = (unsigned short*)(ws + o_wo);
    unsigned short* se   = (unsigned short*)(ws + o_se);
    float*          eo   = (float*)(ws + o_eo);
    unsigned short* xn   = (unsigned short*)(ws + o_xn);
    unsigned short* yb   = xn;                      // alias: xn dead after Q-GEMM
    unsigned short* qb   = (unsigned short*)(ws + o_qb);
    unsigned short* actb = qb;                      // alias: q dead after attention
    unsigned short* xfn  = (unsigned short*)(ws + o_xfn);
    unsigned short* kb   = (unsigned short*)(ws + o_kb);
    unsigned short* vb   = (unsigned short*)(ws + o_vb);

    // pre-passes
    k_ln<1024><<<7776, 256, 0, stream>>>(x, ln_g, ln_b, xn);
    k_ln<512><<<2464, 256, 0, stream>>>(xf, tln_g, tln_b, xfn);
    k_silu<<<512, 256, 0, stream>>>(emb, se);
    k_cvt_all<<<5120, 256, 0, stream>>>(Wq, Wk, Wv, We, Wo, wqt, wkvt, wet, wot);

    // eo = silu(emb0) @ We + be  (f32 out)
    k_mm<3><<<16, 256, 0, stream>>>(se, wet, be, nullptr,
                                    nullptr, nullptr, eo, nullptr, 2048, 1024);

    // projections
    k_mm<0><<<243 * 8, 256, 0, stream>>>(xn, wqt, bq, nullptr,
                                         qb, nullptr, nullptr, nullptr, 1024, 1024);
    k_mm<2><<<77 * 16, 256, 0, stream>>>(xfn, wkvt, bk, bv,
                                         kb, vb, nullptr, nullptr, 2048, 512);

    // attention
    k_attn_m<<<2048, 256, 0, stream>>>(qb, kb, vb, yb);

    // stylization
    k_act<<<7776, 256, 0, stream>>>(yb, eo, ln2_g, ln2_b, actb);

    // output projection + residual -> d_out (f32)
    k_mm<1><<<243 * 8, 256, 0, stream>>>(actb, wot, bo, nullptr,
                                         nullptr, nullptr, outp, x, 1024, 1024);
}

// Round 14
// 391.326 us; speedup vs baseline: 56.6059x; 1.0033x over previous
//
#include <hip/hip_runtime.h>
#include <cstdint>

typedef __attribute__((ext_vector_type(8))) __bf16 bf16x8;
typedef __attribute__((ext_vector_type(4))) float f32x4;
typedef __attribute__((ext_vector_type(8))) unsigned short ushort8v;

__device__ __forceinline__ float b2f(unsigned short u) {
    union { uint32_t i; float f; } w; w.i = ((uint32_t)u) << 16; return w.f;
}
__device__ __forceinline__ unsigned short f2b(float f) {
    union { uint32_t i; float f; } w; w.f = f;
    uint32_t r = (w.i + 0x7FFFu + ((w.i >> 16) & 1u)) >> 16;
    return (unsigned short)r;
}

// 16B global -> LDS direct (wave-uniform LDS base; HW adds lane*16).
__device__ __forceinline__ void gl16(const unsigned short* g, unsigned short* l) {
    __builtin_amdgcn_global_load_lds(
        (const __attribute__((address_space(1))) void*)g,
        (__attribute__((address_space(3))) void*)l,
        16, 0, 0);
}

// ---------------------------------------------------------------------------
// All weight convert+transposes in ONE kernel: block-range dispatch.
// ---------------------------------------------------------------------------
__global__ __launch_bounds__(256) void k_cvt_all(
    const float* __restrict__ Wq, const float* __restrict__ Wk,
    const float* __restrict__ Wv, const float* __restrict__ We,
    const float* __restrict__ Wo,
    unsigned short* __restrict__ wqt, unsigned short* __restrict__ wkvt,
    unsigned short* __restrict__ wet, unsigned short* __restrict__ wot) {
    __shared__ float s[32][33];
    int bid = blockIdx.x;
    const float* in; unsigned short* out; int R, C;
    if (bid < 1024)      { in = Wq; out = wqt;              R = 1024; C = 1024; }
    else if (bid < 1536) { bid -= 1024; in = Wk; out = wkvt;             R = 512;  C = 1024; }
    else if (bid < 2048) { bid -= 1536; in = Wv; out = wkvt + 1024 * 512; R = 512;  C = 1024; }
    else if (bid < 4096) { bid -= 2048; in = We; out = wet;              R = 1024; C = 2048; }
    else                 { bid -= 4096; in = Wo; out = wot;              R = 1024; C = 1024; }
    const int ctiles = C >> 5;
    const int c0 = (bid % ctiles) * 32, r0 = (bid / ctiles) * 32;
    const int tx = threadIdx.x & 31, ty = threadIdx.x >> 5;
#pragma unroll
    for (int i = 0; i < 4; ++i)
        s[ty + i * 8][tx] = in[(size_t)(r0 + ty + i * 8) * C + c0 + tx];
    __syncthreads();
#pragma unroll
    for (int i = 0; i < 4; ++i)
        out[(size_t)(c0 + ty + i * 8) * R + r0 + tx] = f2b(s[tx][ty + i * 8]);
}

// ---------------------------------------------------------------------------
// LayerNorm f32 -> bf16, one wave per row (vectorized)
// ---------------------------------------------------------------------------
template <int DIM>
__global__ __launch_bounds__(256) void k_ln(const float* __restrict__ in,
                                            const float* __restrict__ g,
                                            const float* __restrict__ b,
                                            unsigned short* __restrict__ out) {
    const int row = blockIdx.x * 4 + (threadIdx.x >> 6);
    const int ln = threadIdx.x & 63;
    constexpr int PL = DIM / 64;
    float v[PL];
    const size_t base = (size_t)row * DIM + (size_t)ln * PL;
    const float4* p4 = (const float4*)(in + base);
#pragma unroll
    for (int c = 0; c < PL / 4; ++c) {
        const float4 t = p4[c];
        v[c * 4 + 0] = t.x; v[c * 4 + 1] = t.y; v[c * 4 + 2] = t.z; v[c * 4 + 3] = t.w;
    }
    float s = 0.f, s2 = 0.f;
#pragma unroll
    for (int c = 0; c < PL; ++c) { s += v[c]; s2 += v[c] * v[c]; }
    for (int o = 1; o < 64; o <<= 1) { s += __shfl_xor(s, o); s2 += __shfl_xor(s2, o); }
    const float mean = s / DIM;
    const float rstd = rsqrtf(s2 / DIM - mean * mean + 1e-5f);
    const float4* g4 = (const float4*)(g + ln * PL);
    const float4* b4 = (const float4*)(b + ln * PL);
#pragma unroll
    for (int c0 = 0; c0 < PL; c0 += 8) {
        ushort8v yv;
#pragma unroll
        for (int j = 0; j < 8; ++j) {
            const int c = c0 + j;
            const float gg = ((const float*)g4)[c];
            const float bb = ((const float*)b4)[c];
            yv[j] = f2b((v[c] - mean) * rstd * gg + bb);
        }
        *(ushort8v*)(out + base + c0) = yv;
    }
}

__global__ __launch_bounds__(256) void k_silu(const float* __restrict__ emb,
                                              unsigned short* __restrict__ se) {
    const int i = blockIdx.x * 256 + threadIdx.x;
    const int b = i >> 10, k = i & 1023;
    const float f = emb[(size_t)b * (243 * 1024) + k];
    se[i] = f2b(f / (1.f + __expf(-f)));
}

// ---------------------------------------------------------------------------
// MFMA GEMM (validated r11/r12): m97 staging + bijective XCD n-inner swizzle.
// r14: __launch_bounds__(256, 4) -> 4 blocks/CU resident (VGPR 64, LDS 32KB
// both permit it); cross-block overlap hides the staging barrier drain.
// EPI 0: C0 bf16 | EPI 1: Cf f32 = acc+bias+X | EPI 2: KV split | EPI 3: Cf f32
// ---------------------------------------------------------------------------
template <int EPI>
__global__ __launch_bounds__(256, 4) void k_mm(
    const unsigned short* __restrict__ A, const unsigned short* __restrict__ Bt,
    const float* __restrict__ bias0, const float* __restrict__ bias1,
    unsigned short* __restrict__ C0, unsigned short* __restrict__ C1,
    float* __restrict__ Cf, const float* __restrict__ X,
    int N, int K) {
    __shared__ __align__(16) unsigned short sA[128 * 64];
    __shared__ __align__(16) unsigned short sB[128 * 64];
    const int tid = threadIdx.x, wv = tid >> 6, ln = tid & 63;
    const int wm = wv >> 1, wn = wv & 1;
    const int ln15 = ln & 15, lg = ln >> 4;

    const int NN = N >> 7;
    const int nwg = gridDim.x;
    const int wg = blockIdx.x;
    const int q = nwg >> 3, r = nwg & 7;
    const int xcd = wg & 7, idx = wg >> 3;
    const int u = (xcd < r) ? (xcd * (q + 1) + idx)
                            : (r * (q + 1) + (xcd - r) * q + idx);
    const int m0 = (u / NN) * 128, n0 = (u % NN) * 128;

    const f32x4 fz = {0.f, 0.f, 0.f, 0.f};
    f32x4 acc[4][4];
#pragma unroll
    for (int i = 0; i < 4; ++i)
#pragma unroll
        for (int j = 0; j < 4; ++j) acc[i][j] = fz;

    const int lrow = ln >> 3;
    const int sslot = (ln & 7) ^ lrow;
    const unsigned short* ga = A + (size_t)(m0 + wv * 32 + lrow) * K + sslot * 8;
    const unsigned short* gb = Bt + (size_t)(n0 + wv * 32 + lrow) * K + sslot * 8;
    unsigned short* const lA = sA + (wv * 32) * 64;
    unsigned short* const lB = sB + (wv * 32) * 64;

    for (int k0 = 0; k0 < K; k0 += 64) {
#pragma unroll
        for (int i = 0; i < 4; ++i) {
            gl16(ga + k0 + (size_t)i * 8 * K, lA + i * 8 * 64);
            gl16(gb + k0 + (size_t)i * 8 * K, lB + i * 8 * 64);
        }
        __syncthreads();
        bf16x8 af[4][2], bf[4][2];
#pragma unroll
        for (int i = 0; i < 4; ++i) {
            const int ra2 = wm * 64 + i * 16 + ln15;
            const int rb2 = wn * 64 + i * 16 + ln15;
#pragma unroll
            for (int ks = 0; ks < 2; ++ks) {
                const int slot = ks * 4 + lg;
                af[i][ks] = *(const bf16x8*)(sA + ra2 * 64 + ((slot ^ (ra2 & 7)) * 8));
                bf[i][ks] = *(const bf16x8*)(sB + rb2 * 64 + ((slot ^ (rb2 & 7)) * 8));
            }
        }
#pragma unroll
        for (int mi = 0; mi < 4; ++mi)
#pragma unroll
            for (int ni = 0; ni < 4; ++ni) {
                acc[mi][ni] = __builtin_amdgcn_mfma_f32_16x16x32_bf16(af[mi][0], bf[ni][0], acc[mi][ni], 0, 0, 0);
                acc[mi][ni] = __builtin_amdgcn_mfma_f32_16x16x32_bf16(af[mi][1], bf[ni][1], acc[mi][ni], 0, 0, 0);
            }
        __syncthreads();
    }

    const int colB = n0 + wn * 64;
    const int rowB = m0 + wm * 64;
#pragma unroll
    for (int mi = 0; mi < 4; ++mi) {
#pragma unroll
        for (int ni = 0; ni < 4; ++ni) {
            const int col = colB + ni * 16 + ln15;
            const int row = rowB + mi * 16 + lg * 4;
            float bvv;
            if (EPI == 2) bvv = (col < 1024) ? bias0[col] : bias1[col - 1024];
            else bvv = bias0[col];
#pragma unroll
            for (int r2 = 0; r2 < 4; ++r2) {
                const float v = acc[mi][ni][r2] + bvv;
                if (EPI == 0) {
                    C0[(size_t)(row + r2) * N + col] = f2b(v);
                } else if (EPI == 1) {
                    Cf[(size_t)(row + r2) * N + col] = v + X[(size_t)(row + r2) * N + col];
                } else if (EPI == 2) {
                    if (col < 1024) C0[(size_t)(row + r2) * 1024 + col] = f2b(v);
                    else C1[(size_t)(row + r2) * 1024 + (col - 1024)] = f2b(v);
                } else {
                    Cf[(size_t)(row + r2) * N + col] = v;
                }
            }
        }
    }
}

// ---------------------------------------------------------------------------
// MFMA cross-attention (validated r9/r13): one block per (b,h), 1 barrier.
// ---------------------------------------------------------------------------
__global__ __launch_bounds__(256, 2) void k_attn_m(const unsigned short* __restrict__ Q,
                                                   const unsigned short* __restrict__ Kb,
                                                   const unsigned short* __restrict__ Vb,
                                                   unsigned short* __restrict__ Y) {
    __shared__ __align__(16) unsigned short sK[80 * 64];
    __shared__ __align__(16) unsigned short sV[64 * 96];
    __shared__ __align__(16) unsigned short sP[4][16 * 104];
    const int bh = blockIdx.x;
    const int b = bh >> 4, h = bh & 15;
    const int tid = threadIdx.x, wv = tid >> 6, ln = tid & 63;
    const int ln15 = ln & 15, lg = ln >> 4;

    for (int c = tid; c < 640; c += 256) {
        const int n = c >> 3, ci = c & 7;
        uint4 val = make_uint4(0u, 0u, 0u, 0u);
        if (n < 77) val = *(const uint4*)(Kb + (size_t)(b * 77 + n) * 1024 + h * 64 + ci * 8);
        *(uint4*)((char*)sK + n * 128 + ((ci * 16) ^ ((n & 7) << 4))) = val;
    }
    for (int i = tid; i < 64 * 96; i += 256) {
        const int d = i / 96, n = i - d * 96;
        unsigned short val = 0;
        if (n < 77) val = Vb[(size_t)(b * 77 + n) * 1024 + h * 64 + d];
        sV[i] = val;
    }
    for (int i = ln; i < 16 * 24; i += 64) {
        const int rr = i / 24, cc = i - rr * 24;
        sP[wv][rr * 104 + 80 + cc] = 0;
    }
    bf16x8 qf[4][2];
    const size_t qbase = (size_t)b * (243 * 1024) + h * 64;
#pragma unroll
    for (int mi = 0; mi < 4; ++mi) {
        int t = wv * 64 + mi * 16 + ln15;
        if (t > 242) t = 242;
#pragma unroll
        for (int ks = 0; ks < 2; ++ks)
            qf[mi][ks] = *(const bf16x8*)(Q + qbase + (size_t)t * 1024 + ks * 32 + lg * 8);
    }
    __syncthreads();

    const f32x4 fz = {0.f, 0.f, 0.f, 0.f};
    f32x4 yacc[4][4];
#pragma unroll
    for (int i = 0; i < 4; ++i)
#pragma unroll
        for (int j = 0; j < 4; ++j) yacc[i][j] = fz;

#pragma unroll
    for (int mi = 0; mi < 4; ++mi) {
        f32x4 sc[5];
#pragma unroll
        for (int ci = 0; ci < 5; ++ci) sc[ci] = fz;
#pragma unroll
        for (int ci = 0; ci < 5; ++ci) {
            const int n = ci * 16 + ln15;
#pragma unroll
            for (int ks = 0; ks < 2; ++ks) {
                const int kk = ks * 32 + lg * 8;
                bf16x8 kf = *(const bf16x8*)((const char*)sK + n * 128 + ((kk * 2) ^ ((n & 7) << 4)));
                sc[ci] = __builtin_amdgcn_mfma_f32_16x16x32_bf16(qf[mi][ks], kf, sc[ci], 0, 0, 0);
            }
        }
#pragma unroll
        for (int r = 0; r < 4; ++r) {
            float e[5];
            float mx = -1e30f;
#pragma unroll
            for (int ci = 0; ci < 5; ++ci) {
                const int n = ci * 16 + ln15;
                const float vv = (n < 77) ? sc[ci][r] * 0.125f : -1e30f;
                e[ci] = vv;
                mx = fmaxf(mx, vv);
            }
            mx = fmaxf(mx, __shfl_xor(mx, 1));
            mx = fmaxf(mx, __shfl_xor(mx, 2));
            mx = fmaxf(mx, __shfl_xor(mx, 4));
            mx = fmaxf(mx, __shfl_xor(mx, 8));
            float ssum = 0.f;
#pragma unroll
            for (int ci = 0; ci < 5; ++ci) {
                const int n = ci * 16 + ln15;
                const float ev = (n < 77) ? __expf(e[ci] - mx) : 0.f;
                e[ci] = ev;
                ssum += ev;
            }
            ssum += __shfl_xor(ssum, 1);
            ssum += __shfl_xor(ssum, 2);
            ssum += __shfl_xor(ssum, 4);
            ssum += __shfl_xor(ssum, 8);
            const float inv = 1.f / ssum;
            const int prow = lg * 4 + r;
#pragma unroll
            for (int ci = 0; ci < 5; ++ci)
                sP[wv][prow * 104 + ci * 16 + ln15] = f2b(e[ci] * inv);
        }
#pragma unroll
        for (int ks = 0; ks < 3; ++ks) {
            bf16x8 pa = *(const bf16x8*)(sP[wv] + ln15 * 104 + ks * 32 + lg * 8);
#pragma unroll
            for (int di = 0; di < 4; ++di) {
                bf16x8 vf = *(const bf16x8*)(sV + (di * 16 + ln15) * 96 + ks * 32 + lg * 8);
                yacc[mi][di] = __builtin_amdgcn_mfma_f32_16x16x32_bf16(pa, vf, yacc[mi][di], 0, 0, 0);
            }
        }
    }
    const size_t ybase = (size_t)b * (243 * 1024) + h * 64;
#pragma unroll
    for (int mi = 0; mi < 4; ++mi)
#pragma unroll
        for (int di = 0; di < 4; ++di)
#pragma unroll
            for (int r = 0; r < 4; ++r) {
                const int t = wv * 64 + mi * 16 + lg * 4 + r;
                if (t < 243) Y[ybase + (size_t)t * 1024 + di * 16 + ln15] = f2b(yacc[mi][di][r]);
            }
}

// ---------------------------------------------------------------------------
// Stylization (vectorized, validated)
// ---------------------------------------------------------------------------
__global__ __launch_bounds__(256) void k_act(const unsigned short* __restrict__ y,
                                             const float* __restrict__ eo,
                                             const float* __restrict__ g,
                                             const float* __restrict__ b,
                                             unsigned short* __restrict__ out) {
    const int row = blockIdx.x * 4 + (threadIdx.x >> 6);
    const int ln = threadIdx.x & 63;
    const int bb = row / 243;
    float v[16];
    const size_t base = (size_t)row * 1024 + ln * 16;
#pragma unroll
    for (int c0 = 0; c0 < 16; c0 += 8) {
        const ushort8v t = *(const ushort8v*)(y + base + c0);
#pragma unroll
        for (int j = 0; j < 8; ++j) v[c0 + j] = b2f(t[j]);
    }
    float s = 0.f, s2 = 0.f;
#pragma unroll
    for (int c = 0; c < 16; ++c) { s += v[c]; s2 += v[c] * v[c]; }
    for (int o = 1; o < 64; o <<= 1) { s += __shfl_xor(s, o); s2 += __shfl_xor(s2, o); }
    const float mean = s / 1024.f;
    const float rstd = rsqrtf(s2 / 1024.f - mean * mean + 1e-5f);
    const float* gp = g + ln * 16;
    const float* bp = b + ln * 16;
    const float* sc = eo + (size_t)bb * 2048 + ln * 16;
    const float* sh = sc + 1024;
#pragma unroll
    for (int c0 = 0; c0 < 16; c0 += 8) {
        ushort8v yv;
#pragma unroll
        for (int j = 0; j < 8; ++j) {
            const int c = c0 + j;
            const float nl = (v[c] - mean) * rstd * gp[c] + bp[c];
            const float hh = nl * (1.f + sc[c]) + sh[c];
            yv[j] = f2b(hh / (1.f + __expf(-hh)));
        }
        *(ushort8v*)(out + base + c0) = yv;
    }
}

// ---------------------------------------------------------------------------
extern "C" void kernel_launch(void* const* d_in, const int* in_sizes, int n_in,
                              void* d_out, int out_size, void* d_ws, size_t ws_size,
                              hipStream_t stream) {
    (void)in_sizes; (void)n_in; (void)out_size; (void)ws_size;

    const float* x     = (const float*)d_in[0];
    const float* xf    = (const float*)d_in[1];
    const float* emb   = (const float*)d_in[2];
    const float* ln_g  = (const float*)d_in[3];
    const float* ln_b  = (const float*)d_in[4];
    const float* tln_g = (const float*)d_in[5];
    const float* tln_b = (const float*)d_in[6];
    const float* Wq    = (const float*)d_in[7];
    const float* bq    = (const float*)d_in[8];
    const float* Wk    = (const float*)d_in[9];
    const float* bk    = (const float*)d_in[10];
    const float* Wv    = (const float*)d_in[11];
    const float* bv    = (const float*)d_in[12];
    const float* We    = (const float*)d_in[13];
    const float* be    = (const float*)d_in[14];
    const float* ln2_g = (const float*)d_in[15];
    const float* ln2_b = (const float*)d_in[16];
    const float* Wo    = (const float*)d_in[17];
    const float* bo    = (const float*)d_in[18];
    float* outp = (float*)d_out;

    char* ws = (char*)d_ws;
    constexpr size_t o_wq   = 0;
    constexpr size_t o_wkv  = o_wq + 2097152;
    constexpr size_t o_we   = o_wkv + 2097152;
    constexpr size_t o_wo   = o_we + 4194304;
    constexpr size_t o_se   = o_wo + 2097152;
    constexpr size_t o_eo   = o_se + 262144;
    constexpr size_t o_xn   = o_eo + 1048576;
    constexpr size_t o_qb   = o_xn + 63700992;
    constexpr size_t o_xfn  = o_qb + 63700992;
    constexpr size_t o_kb   = o_xfn + 10092544;
    constexpr size_t o_vb   = o_kb + 20185088;

    unsigned short* wqt  = (unsigned short*)(ws + o_wq);
    unsigned short* wkvt = (unsigned short*)(ws + o_wkv);
    unsigned short* wet  = (unsigned short*)(ws + o_we);
    unsigned short* wot  = (unsigned short*)(ws + o_wo);
    unsigned short* se   = (unsigned short*)(ws + o_se);
    float*          eo   = (float*)(ws + o_eo);
    unsigned short* xn   = (unsigned short*)(ws + o_xn);
    unsigned short* yb   = xn;                      // alias: xn dead after Q-GEMM
    unsigned short* qb   = (unsigned short*)(ws + o_qb);
    unsigned short* actb = qb;                      // alias: q dead after attention
    unsigned short* xfn  = (unsigned short*)(ws + o_xfn);
    unsigned short* kb   = (unsigned short*)(ws + o_kb);
    unsigned short* vb   = (unsigned short*)(ws + o_vb);

    // pre-passes
    k_ln<1024><<<7776, 256, 0, stream>>>(x, ln_g, ln_b, xn);
    k_ln<512><<<2464, 256, 0, stream>>>(xf, tln_g, tln_b, xfn);
    k_silu<<<512, 256, 0, stream>>>(emb, se);
    k_cvt_all<<<5120, 256, 0, stream>>>(Wq, Wk, Wv, We, Wo, wqt, wkvt, wet, wot);

    // eo = silu(emb0) @ We + be  (f32 out)
    k_mm<3><<<16, 256, 0, stream>>>(se, wet, be, nullptr,
                                    nullptr, nullptr, eo, nullptr, 2048, 1024);

    // projections
    k_mm<0><<<243 * 8, 256, 0, stream>>>(xn, wqt, bq, nullptr,
                                         qb, nullptr, nullptr, nullptr, 1024, 1024);
    k_mm<2><<<77 * 16, 256, 0, stream>>>(xfn, wkvt, bk, bv,
                                         kb, vb, nullptr, nullptr, 2048, 512);

    // attention
    k_attn_m<<<2048, 256, 0, stream>>>(qb, kb, vb, yb);

    // stylization
    k_act<<<7776, 256, 0, stream>>>(yb, eo, ln2_g, ln2_b, actb);

    // output projection + residual -> d_out (f32)
    k_mm<1><<<243 * 8, 256, 0, stream>>>(actb, wot, bo, nullptr,
                                         nullptr, nullptr, outp, x, 1024, 1024);
}